// Round 1
// baseline (1049.245 us; speedup 1.0000x reference)
//
#include <hip/hip_runtime.h>

#define NNODES 100000
#define NEDGES 1600000
#define ET (NEDGES + NNODES)      // 1,700,000 incl. self loops
#define NPAD (49 * 2048)          // 100352, scan padding
#define NCLS 40
#define NEG 0.2f
#define BNEPS 1e-5f

// ---------------- edge decode (int32 vs int64 hedge) ----------------
__device__ __forceinline__ int edge_src(const int* ei, int e, int w64) {
    if (e >= NEDGES) return e - NEDGES;          // self loop
    return w64 ? ei[2 * e] : ei[e];
}
__device__ __forceinline__ int edge_dst(const int* ei, int e, int w64) {
    if (e >= NEDGES) return e - NEDGES;
    return w64 ? ei[2 * (NEDGES + e)] : ei[NEDGES + e];
}

__global__ void k_detect(const int* ei, int* flag) {
    if (blockIdx.x == 0 && threadIdx.x == 0) {
        int is64 = 1;
        for (int j = 1; j < 16; j += 2)
            if (ei[j] != 0) is64 = 0;   // int64 high words are 0 (ids < 2^31)
        *flag = is64;
    }
}

// ---------------- counting sort by dst ----------------
__global__ void k_hist(const int* __restrict__ ei, const int* flag, int* cnt) {
    int e = blockIdx.x * 256 + threadIdx.x;
    if (e >= ET) return;
    int w64 = *flag;
    atomicAdd(&cnt[edge_dst(ei, e, w64)], 1);
}

__global__ __launch_bounds__(256) void k_scan1(const int* __restrict__ cnt,
                                               int* starts, int* bsum) {
    __shared__ int sh[256];
    int t = threadIdx.x;
    int base = blockIdx.x * 2048 + t * 8;
    int v[8], pre[8], s = 0;
#pragma unroll
    for (int i = 0; i < 8; i++) { v[i] = cnt[base + i]; pre[i] = s; s += v[i]; }
    sh[t] = s;
    __syncthreads();
    for (int off = 1; off < 256; off <<= 1) {
        int add = (t >= off) ? sh[t - off] : 0;
        __syncthreads();
        sh[t] += add;
        __syncthreads();
    }
    int excl = sh[t] - s;
#pragma unroll
    for (int i = 0; i < 8; i++) starts[base + i] = excl + pre[i];
    if (t == 255) bsum[blockIdx.x] = sh[255];
}

__global__ void k_scan2(int* bsum) {
    if (threadIdx.x == 0) {
        int run = 0;
        for (int i = 0; i < 49; i++) { int t = bsum[i]; bsum[i] = run; run += t; }
    }
}

__global__ void k_scan3(int* rowptr, const int* __restrict__ bsum, int* writeptr) {
    int i = blockIdx.x * 256 + threadIdx.x;   // grid covers NPAD
    if (i < NNODES) {
        int r = rowptr[i] + bsum[i >> 11];
        rowptr[i] = r;
        writeptr[i] = r;
    } else if (i == NNODES) {
        rowptr[NNODES] = ET;
    }
}

__global__ void k_scatter(const int* __restrict__ ei, const int* flag,
                          int* writeptr, int* __restrict__ srcs) {
    int e = blockIdx.x * 256 + threadIdx.x;
    if (e >= ET) return;
    int w64 = *flag;
    int src = edge_src(ei, e, w64);
    int dst = edge_dst(ei, e, w64);
    int pos = atomicAdd(&writeptr[dst], 1);
    srcs[pos] = src;
}

// ---------------- GEMM: C[n,128] = A[n,128] @ W[128,128] ----------------
__global__ __launch_bounds__(256) void k_gemm128(const float* __restrict__ A,
                                                 const float* __restrict__ W,
                                                 float* __restrict__ C, int n) {
    __shared__ float xT[32][68];    // [k][row], pad 68 -> conflict-free
    __shared__ float wt[32][128];   // [k][col]
    int t = threadIdx.x;
    int ty = t >> 4, tx = t & 15;   // 16x16 threads; 4 rows x 8 cols each
    int row0 = blockIdx.x * 64;
    int lr = t >> 3;                // 0..31 (load row)
    int lk = (t & 7) * 4;           // 0..28 (load k base)
    float acc[4][8] = {};

    for (int kc = 0; kc < 128; kc += 32) {
        float4 a0 = make_float4(0.f, 0.f, 0.f, 0.f), a1 = a0;
        if (row0 + lr < n)      a0 = *(const float4*)&A[(size_t)(row0 + lr) * 128 + kc + lk];
        if (row0 + lr + 32 < n) a1 = *(const float4*)&A[(size_t)(row0 + lr + 32) * 128 + kc + lk];
        float4 wv[4];
#pragma unroll
        for (int j = 0; j < 4; j++) {
            int s = t + j * 256;
            wv[j] = *(const float4*)&W[(kc + (s >> 5)) * 128 + (s & 31) * 4];
        }
        __syncthreads();   // previous tile's reads done
        xT[lk + 0][lr] = a0.x; xT[lk + 1][lr] = a0.y;
        xT[lk + 2][lr] = a0.z; xT[lk + 3][lr] = a0.w;
        xT[lk + 0][lr + 32] = a1.x; xT[lk + 1][lr + 32] = a1.y;
        xT[lk + 2][lr + 32] = a1.z; xT[lk + 3][lr + 32] = a1.w;
#pragma unroll
        for (int j = 0; j < 4; j++) {
            int s = t + j * 256;
            *(float4*)&wt[s >> 5][(s & 31) * 4] = wv[j];
        }
        __syncthreads();
#pragma unroll 8
        for (int k = 0; k < 32; k++) {
            float4 av = *(const float4*)&xT[k][ty * 4];
            float4 b0 = *(const float4*)&wt[k][tx * 8];
            float4 b1 = *(const float4*)&wt[k][tx * 8 + 4];
            float a[4] = {av.x, av.y, av.z, av.w};
            float b[8] = {b0.x, b0.y, b0.z, b0.w, b1.x, b1.y, b1.z, b1.w};
#pragma unroll
            for (int i = 0; i < 4; i++)
#pragma unroll
                for (int j = 0; j < 8; j++) acc[i][j] += a[i] * b[j];
        }
    }
#pragma unroll
    for (int i = 0; i < 4; i++) {
        int row = row0 + ty * 4 + i;
        if (row < n) {
            *(float4*)&C[(size_t)row * 128 + tx * 8] =
                make_float4(acc[i][0], acc[i][1], acc[i][2], acc[i][3]);
            *(float4*)&C[(size_t)row * 128 + tx * 8 + 4] =
                make_float4(acc[i][4], acc[i][5], acc[i][6], acc[i][7]);
        }
    }
}

// ---------------- attention scores: es = h@a_s, ed = h@a_d ----------------
__global__ __launch_bounds__(256) void k_scores(const float* __restrict__ h,
                                                const float* __restrict__ a_s,
                                                const float* __restrict__ a_d,
                                                float* es, float* ed, int n) {
    int w = (blockIdx.x * 256 + threadIdx.x) >> 6;
    if (w >= n) return;
    int lane = threadIdx.x & 63;
    float2 hv = ((const float2*)h)[(size_t)w * 64 + lane];
    float2 as2 = ((const float2*)a_s)[lane];
    float2 ad2 = ((const float2*)a_d)[lane];
    float s1 = hv.x * as2.x + hv.y * as2.y;
    float s2 = hv.x * ad2.x + hv.y * ad2.y;
    for (int off = 32; off; off >>= 1) {
        s1 += __shfl_xor(s1, off, 64);
        s2 += __shfl_xor(s2, off, 64);
    }
    if (lane == 0) { es[w] = s1; ed[w] = s2; }
}

// ---------------- per-dst online-softmax aggregation ----------------
__global__ __launch_bounds__(256) void k_aggregate(const float* __restrict__ h,
                                                   const int* __restrict__ srcs,
                                                   const int* __restrict__ rowptr,
                                                   const float* __restrict__ es,
                                                   const float* __restrict__ ed,
                                                   const float* __restrict__ bias,
                                                   float* __restrict__ hout, int n) {
    int w = (blockIdx.x * 256 + threadIdx.x) >> 6;
    if (w >= n) return;
    int lane = threadIdx.x & 63;
    int start = rowptr[w], end = rowptr[w + 1];
    float edv = ed[w];
    const float2* hp = (const float2*)h;
    float2 acc = make_float2(0.f, 0.f);
    float m = -3.0e38f, den = 0.f;
    for (int idx = start; idx < end; ++idx) {
        int s = srcs[idx];
        float e = es[s] + edv;
        e = e > 0.f ? e : NEG * e;
        float mn = fmaxf(m, e);
        float sc = __expf(m - mn);     // 0 on first iter
        float p = __expf(e - mn);
        float2 hv = hp[(size_t)s * 64 + lane];
        den = den * sc + p;
        acc.x = acc.x * sc + p * hv.x;
        acc.y = acc.y * sc + p * hv.y;
        m = mn;
    }
    float inv = 1.f / den;             // den>0: self loop guaranteed
    float2 b2 = ((const float2*)bias)[lane];
    ((float2*)hout)[(size_t)w * 64 + lane] =
        make_float2(acc.x * inv + b2.x, acc.y * inv + b2.y);
}

// ---------------- BatchNorm stats / finalize / apply+ELU ----------------
__global__ __launch_bounds__(256) void k_bnstats(const float* __restrict__ hin,
                                                 float* sums, float* sqs, int n) {
    __shared__ float ls[128], lq[128];
    int t = threadIdx.x;
    int c = t & 127, half = t >> 7;
    int r0 = blockIdx.x * 512;
    int rend = min(r0 + 512, n);
    float s = 0.f, q = 0.f;
    for (int r = r0 + half; r < rend; r += 2) {
        float v = hin[(size_t)r * 128 + c];
        s += v; q += v * v;
    }
    if (half) { ls[c] = s; lq[c] = q; }
    __syncthreads();
    if (!half) {
        s += ls[c]; q += lq[c];
        atomicAdd(&sums[c], s);
        atomicAdd(&sqs[c], q);
    }
}

__global__ void k_bnfinal(const float* sums, const float* sqs,
                          const float* gamma, const float* beta,
                          float* sc, float* sh) {
    int c = threadIdx.x;
    float mu = sums[c] / (float)NNODES;
    float var = sqs[c] / (float)NNODES - mu * mu;
    var = fmaxf(var, 0.f);
    float inv = rsqrtf(var + BNEPS);
    float s = gamma[c] * inv;
    sc[c] = s;
    sh[c] = beta[c] - mu * s;
}

__global__ __launch_bounds__(256) void k_bnapply(float* __restrict__ h,
                                                 const float* __restrict__ sc,
                                                 const float* __restrict__ sh) {
    int i = blockIdx.x * 256 + threadIdx.x;   // float4 index, 3.2M total
    int c = (i & 31) * 4;
    float4 v = ((float4*)h)[i];
    float z;
    z = v.x * sc[c + 0] + sh[c + 0]; v.x = z > 0.f ? z : (__expf(z) - 1.f);
    z = v.y * sc[c + 1] + sh[c + 1]; v.y = z > 0.f ? z : (__expf(z) - 1.f);
    z = v.z * sc[c + 2] + sh[c + 2]; v.z = z > 0.f ? z : (__expf(z) - 1.f);
    z = v.w * sc[c + 3] + sh[c + 3]; v.w = z > 0.f ? z : (__expf(z) - 1.f);
    ((float4*)h)[i] = v;
}

// ---------------- output head: out[n,40] = h@Wout + bout ----------------
__global__ __launch_bounds__(256) void k_outgemm(const float* __restrict__ h,
                                                 const float* __restrict__ Wout,
                                                 const float* __restrict__ bout,
                                                 float* __restrict__ out, int n) {
    __shared__ float lwT[40][128];      // transposed Wout
    __shared__ float lh[64][132];       // 64 rows staged
    __shared__ float lb[40];
    int t = threadIdx.x;
    for (int idx = t; idx < 128 * 40; idx += 256) {
        int r = idx / 40, c = idx % 40;
        lwT[c][r] = Wout[idx];
    }
    if (t < 40) lb[t] = bout[t];
    int n0 = blockIdx.x * 64;
#pragma unroll
    for (int j = 0; j < 8; j++) {
        int s = t + j * 256;            // 2048 float4 slots
        int r = s >> 5, c4 = s & 31;
        float4 v = make_float4(0.f, 0.f, 0.f, 0.f);
        if (n0 + r < n) v = ((const float4*)h)[(size_t)(n0 + r) * 32 + c4];
        *(float4*)&lh[r][c4 * 4] = v;
    }
    __syncthreads();
    int nl = t & 63, g = t >> 6;        // 4 groups x 10 cols
    int row = n0 + nl;
    if (row >= n) return;
    float acc[10] = {};
    for (int k = 0; k < 128; k += 4) {
        float4 hv = *(const float4*)&lh[nl][k];
#pragma unroll
        for (int j = 0; j < 10; j++) {
            float4 wv = *(const float4*)&lwT[g * 10 + j][k];
            acc[j] += hv.x * wv.x + hv.y * wv.y + hv.z * wv.z + hv.w * wv.w;
        }
    }
#pragma unroll
    for (int j = 0; j < 10; j++)
        out[(size_t)row * 40 + g * 10 + j] = acc[j] + lb[g * 10 + j];
}

// ---------------- launch ----------------
extern "C" void kernel_launch(void* const* d_in, const int* in_sizes, int n_in,
                              void* d_out, int out_size, void* d_ws, size_t ws_size,
                              hipStream_t stream) {
    const float* x      = (const float*)d_in[0];
    const int*   ei     = (const int*)d_in[1];
    const float* W1     = (const float*)d_in[2];
    const float* a_src1 = (const float*)d_in[3];
    const float* a_dst1 = (const float*)d_in[4];
    const float* b1     = (const float*)d_in[5];
    const float* W2     = (const float*)d_in[6];
    const float* a_src2 = (const float*)d_in[7];
    const float* a_dst2 = (const float*)d_in[8];
    const float* b2     = (const float*)d_in[9];
    const float* gamma  = (const float*)d_in[10];
    const float* beta   = (const float*)d_in[11];
    const float* Wout   = (const float*)d_in[12];
    const float* bout   = (const float*)d_in[13];
    float* out = (float*)d_out;

    char* p = (char*)d_ws;
    auto alloc = [&](size_t bytes) -> void* {
        void* r = (void*)p;
        p += (bytes + 255) & ~(size_t)255;
        return r;
    };
    float* h      = (float*)alloc((size_t)NNODES * 128 * 4);
    float* hagg   = (float*)alloc((size_t)NNODES * 128 * 4);
    float* es     = (float*)alloc((size_t)NNODES * 4);
    float* ed     = (float*)alloc((size_t)NNODES * 4);
    int*   rowptr = (int*)alloc((size_t)(NPAD + 1) * 4);
    int*   wptr   = (int*)alloc((size_t)NNODES * 4);
    int*   cnt    = (int*)alloc((size_t)NPAD * 4);
    int*   srcs   = (int*)alloc((size_t)ET * 4);
    int*   bsum   = (int*)alloc(64 * 4);
    float* bnstat = (float*)alloc(4 * 128 * 4);   // sum1,sq1,sum2,sq2
    float* bnsc   = (float*)alloc(128 * 4);
    float* bnsh   = (float*)alloc(128 * 4);
    int*   flag   = (int*)alloc(4);

    float* sum1 = bnstat, *sq1 = bnstat + 128, *sum2 = bnstat + 256, *sq2 = bnstat + 384;

    hipMemsetAsync(cnt, 0, (size_t)NPAD * 4, stream);
    hipMemsetAsync(bnstat, 0, 4 * 128 * 4, stream);

    const int EB = (ET + 255) / 256;              // 6641
    k_detect<<<1, 64, 0, stream>>>(ei, flag);
    k_hist<<<EB, 256, 0, stream>>>(ei, flag, cnt);
    k_scan1<<<49, 256, 0, stream>>>(cnt, rowptr, bsum);
    k_scan2<<<1, 64, 0, stream>>>(bsum);
    k_scan3<<<NPAD / 256, 256, 0, stream>>>(rowptr, bsum, wptr);
    k_scatter<<<EB, 256, 0, stream>>>(ei, flag, wptr, srcs);

    const int GB = (NNODES + 63) / 64;            // 1563
    const int WB = NNODES / 4;                    // 25000 (exact)
    const int SB = (NNODES + 511) / 512;          // 196

    // ---- layer 1 ----
    k_gemm128<<<GB, 256, 0, stream>>>(x, W1, h, NNODES);
    k_scores<<<WB, 256, 0, stream>>>(h, a_src1, a_dst1, es, ed, NNODES);
    k_aggregate<<<WB, 256, 0, stream>>>(h, srcs, rowptr, es, ed, b1, hagg, NNODES);
    k_bnstats<<<SB, 256, 0, stream>>>(hagg, sum1, sq1, NNODES);
    k_bnfinal<<<1, 128, 0, stream>>>(sum1, sq1, gamma, beta, bnsc, bnsh);
    k_bnapply<<<NNODES / 8, 256, 0, stream>>>(hagg, bnsc, bnsh);   // 12500 blocks

    // ---- layer 2 ----
    k_gemm128<<<GB, 256, 0, stream>>>(hagg, W2, h, NNODES);
    k_scores<<<WB, 256, 0, stream>>>(h, a_src2, a_dst2, es, ed, NNODES);
    k_aggregate<<<WB, 256, 0, stream>>>(h, srcs, rowptr, es, ed, b2, hagg, NNODES);
    k_bnstats<<<SB, 256, 0, stream>>>(hagg, sum2, sq2, NNODES);
    k_bnfinal<<<1, 128, 0, stream>>>(sum2, sq2, gamma, beta, bnsc, bnsh);
    k_bnapply<<<NNODES / 8, 256, 0, stream>>>(hagg, bnsc, bnsh);

    // ---- head ----
    k_outgemm<<<GB, 256, 0, stream>>>(hagg, Wout, bout, out, NNODES);

    (void)in_sizes; (void)n_in; (void)out_size; (void)ws_size;
}

// Round 2
// 891.413 us; speedup vs baseline: 1.1771x; 1.1771x over previous
//
#include <hip/hip_runtime.h>

#define NNODES 100000
#define NEDGES 1600000
#define ET (NEDGES + NNODES)      // 1,700,000 incl. self loops
#define NPAD (49 * 2048)          // 100352, scan padding
#define NCLS 40
#define NEG 0.2f
#define BNEPS 1e-5f

typedef __attribute__((ext_vector_type(8))) short short8;
typedef __attribute__((ext_vector_type(4))) float floatx4;

__device__ __forceinline__ unsigned short f2b(float x) {
    unsigned int u = __float_as_uint(x);
    u += 0x7fff + ((u >> 16) & 1);        // RNE
    return (unsigned short)(u >> 16);
}
__device__ __forceinline__ float blo2f(unsigned int v) {
    return __uint_as_float(v << 16);
}
__device__ __forceinline__ float bhi2f(unsigned int v) {
    return __uint_as_float(v & 0xffff0000u);
}

// ---------------- edge decode (int32 vs int64 hedge) ----------------
__device__ __forceinline__ int edge_src(const int* ei, int e, int w64) {
    if (e >= NEDGES) return e - NEDGES;          // self loop
    return w64 ? ei[2 * e] : ei[e];
}
__device__ __forceinline__ int edge_dst(const int* ei, int e, int w64) {
    if (e >= NEDGES) return e - NEDGES;
    return w64 ? ei[2 * (NEDGES + e)] : ei[NEDGES + e];
}

__global__ void k_detect(const int* ei, int* flag) {
    if (blockIdx.x == 0 && threadIdx.x == 0) {
        int is64 = 1;
        for (int j = 1; j < 16; j += 2)
            if (ei[j] != 0) is64 = 0;   // int64 high words are 0 (ids < 2^31)
        *flag = is64;
    }
}

// ---------------- W transpose + bf16 convert (once) ----------------
__global__ void k_prepW(const float* __restrict__ W1, const float* __restrict__ W2,
                        unsigned short* __restrict__ WT1, unsigned short* __restrict__ WT2) {
    int t = blockIdx.x * 256 + threadIdx.x;      // 16384 threads
    int k = t >> 7, n = t & 127;
    WT1[n * 128 + k] = f2b(W1[t]);
    WT2[n * 128 + k] = f2b(W2[t]);
}

// ---------------- counting sort by dst ----------------
__global__ void k_hist(const int* __restrict__ ei, const int* flag, int* cnt) {
    int e = blockIdx.x * 256 + threadIdx.x;
    if (e >= ET) return;
    int w64 = *flag;
    atomicAdd(&cnt[edge_dst(ei, e, w64)], 1);
}

__global__ __launch_bounds__(256) void k_scan1(const int* __restrict__ cnt,
                                               int* starts, int* bsum) {
    __shared__ int sh[256];
    int t = threadIdx.x;
    int base = blockIdx.x * 2048 + t * 8;
    int v[8], pre[8], s = 0;
#pragma unroll
    for (int i = 0; i < 8; i++) { v[i] = cnt[base + i]; pre[i] = s; s += v[i]; }
    sh[t] = s;
    __syncthreads();
    for (int off = 1; off < 256; off <<= 1) {
        int add = (t >= off) ? sh[t - off] : 0;
        __syncthreads();
        sh[t] += add;
        __syncthreads();
    }
    int excl = sh[t] - s;
#pragma unroll
    for (int i = 0; i < 8; i++) starts[base + i] = excl + pre[i];
    if (t == 255) bsum[blockIdx.x] = sh[255];
}

__global__ void k_scan2(int* bsum) {
    if (threadIdx.x == 0) {
        int run = 0;
        for (int i = 0; i < 49; i++) { int t = bsum[i]; bsum[i] = run; run += t; }
    }
}

__global__ void k_scan3(int* rowptr, const int* __restrict__ bsum, int* writeptr) {
    int i = blockIdx.x * 256 + threadIdx.x;   // grid covers NPAD
    if (i < NNODES) {
        int r = rowptr[i] + bsum[i >> 11];
        rowptr[i] = r;
        writeptr[i] = r;
    } else if (i == NNODES) {
        rowptr[NNODES] = ET;
    }
}

__global__ void k_scatter(const int* __restrict__ ei, const int* flag,
                          int* writeptr, int* __restrict__ srcs) {
    int e = blockIdx.x * 256 + threadIdx.x;
    if (e >= ET) return;
    int w64 = *flag;
    int src = edge_src(ei, e, w64);
    int dst = edge_dst(ei, e, w64);
    int pos = atomicAdd(&writeptr[dst], 1);
    srcs[pos] = src;
}

// ---------------- MFMA GEMM: hB[n,128](bf16) = A[n,128](f32) @ W ----------------
// WTg is W pre-transposed [n][k], bf16. Full K=128 staged in LDS.
__global__ __launch_bounds__(256) void k_gemm_mfma(const float* __restrict__ A,
                                                   const unsigned short* __restrict__ WTg,
                                                   unsigned short* __restrict__ hB, int n) {
    __shared__ unsigned short lA[64][136];    // [row][k], pad 136 (272B stride, 16B-mult)
    __shared__ unsigned short lW[128][136];   // [ncol][k]
    int t = threadIdx.x;
    int row0 = blockIdx.x * 64;

    // stage W^T: 128 rows x 256B = 2048 uint4
    const uint4* wt4 = (const uint4*)WTg;
#pragma unroll
    for (int j = 0; j < 8; j++) {
        int idx = t + j * 256;
        int nr = idx >> 4, seg = idx & 15;
        uint4 v = wt4[idx];
        *(uint4*)&lW[nr][seg * 8] = v;
    }
    // stage A tile: 64 rows x 128 f32 = 2048 float4, convert to bf16
#pragma unroll
    for (int j = 0; j < 8; j++) {
        int idx = t + j * 256;
        int r = idx >> 5, c4 = idx & 31;
        float4 v = make_float4(0.f, 0.f, 0.f, 0.f);
        if (row0 + r < n) v = ((const float4*)A)[(size_t)(row0 + r) * 32 + c4];
        ushort4 u;
        u.x = f2b(v.x); u.y = f2b(v.y); u.z = f2b(v.z); u.w = f2b(v.w);
        *(ushort4*)&lA[r][c4 * 4] = u;
    }
    __syncthreads();

    int w = t >> 6, lane = t & 63;
    int m = lane & 15, q = lane >> 4;
    int arow = w * 16 + m;
    floatx4 acc[8];
#pragma unroll
    for (int ct = 0; ct < 8; ct++) acc[ct] = (floatx4)0.0f;

#pragma unroll
    for (int kt = 0; kt < 4; kt++) {
        int kb = kt * 32 + q * 8;
        short8 af = *(const short8*)&lA[arow][kb];
#pragma unroll
        for (int ct = 0; ct < 8; ct++) {
            short8 bf = *(const short8*)&lW[ct * 16 + m][kb];
            acc[ct] = __builtin_amdgcn_mfma_f32_16x16x32_bf16(af, bf, acc[ct], 0, 0, 0);
        }
    }

    // epilogue: frag -> LDS (own 16 rows of lA) -> coalesced bf16 store
#pragma unroll
    for (int ct = 0; ct < 8; ct++)
#pragma unroll
        for (int r = 0; r < 4; r++)
            lA[w * 16 + q * 4 + r][ct * 16 + m] = f2b(acc[ct][r]);
#pragma unroll
    for (int j = 0; j < 4; j++) {
        int idx = lane + j * 64;
        int r = idx >> 4, seg = idx & 15;
        int grow = row0 + w * 16 + r;
        if (grow < n) {
            uint4 v = *(const uint4*)&lA[w * 16 + r][seg * 8];
            ((uint4*)hB)[(size_t)grow * 16 + seg] = v;
        }
    }
}

// ---------------- attention scores from bf16 h ----------------
__global__ __launch_bounds__(256) void k_scores(const unsigned short* __restrict__ hB,
                                                const float* __restrict__ a_s,
                                                const float* __restrict__ a_d,
                                                float* es, float* ed, int n) {
    int w = (blockIdx.x * 256 + threadIdx.x) >> 6;
    if (w >= n) return;
    int lane = threadIdx.x & 63;
    unsigned int v = ((const unsigned int*)hB)[(size_t)w * 64 + lane];
    float hx = blo2f(v), hy = bhi2f(v);
    float2 as2 = ((const float2*)a_s)[lane];
    float2 ad2 = ((const float2*)a_d)[lane];
    float s1 = hx * as2.x + hy * as2.y;
    float s2 = hx * ad2.x + hy * ad2.y;
    for (int off = 32; off; off >>= 1) {
        s1 += __shfl_xor(s1, off, 64);
        s2 += __shfl_xor(s2, off, 64);
    }
    if (lane == 0) { es[w] = s1; ed[w] = s2; }
}

// ---------------- per-dst softmax weights (lane-parallel) ----------------
__global__ __launch_bounds__(256) void k_alpha(const int* __restrict__ srcs,
                                               const int* __restrict__ rowptr,
                                               const float* __restrict__ es,
                                               const float* __restrict__ ed,
                                               float* __restrict__ alpha, int n) {
    int w = (blockIdx.x * 256 + threadIdx.x) >> 6;
    if (w >= n) return;
    int lane = threadIdx.x & 63;
    int start = rowptr[w], end = rowptr[w + 1];
    float edv = ed[w];
    // pass 1: max
    float m = -3.0e38f;
    for (int i = start + lane; i < end; i += 64) {
        float e = es[srcs[i]] + edv;
        e = e > 0.f ? e : NEG * e;
        m = fmaxf(m, e);
    }
    for (int off = 32; off; off >>= 1) m = fmaxf(m, __shfl_xor(m, off, 64));
    // pass 2: exp + sum, stash p
    float den = 0.f;
    for (int i = start + lane; i < end; i += 64) {
        float e = es[srcs[i]] + edv;
        e = e > 0.f ? e : NEG * e;
        float p = __expf(e - m);
        alpha[i] = p;
        den += p;
    }
    for (int off = 32; off; off >>= 1) den += __shfl_xor(den, off, 64);
    float inv = 1.f / den;
    // pass 3: normalize
    for (int i = start + lane; i < end; i += 64) alpha[i] *= inv;
}

// ---------------- weighted sum: hagg[dst] = sum alpha * hB[src] + b ----------------
__global__ __launch_bounds__(256) void k_wsum(const unsigned short* __restrict__ hB,
                                              const int* __restrict__ srcs,
                                              const int* __restrict__ rowptr,
                                              const float* __restrict__ alpha,
                                              const float* __restrict__ bias,
                                              float* __restrict__ hagg, int n) {
    int w = (blockIdx.x * 256 + threadIdx.x) >> 6;
    if (w >= n) return;
    int lane = threadIdx.x & 63;
    int start = rowptr[w], end = rowptr[w + 1];
    const unsigned int* hp = (const unsigned int*)hB;
    float ax = 0.f, ay = 0.f;
    for (int chunk = start; chunk < end; chunk += 64) {
        int i = chunk + lane;
        int sv = 0; float av = 0.f;
        if (i < end) { sv = srcs[i]; av = alpha[i]; }
        int cnt = min(64, end - chunk);
        for (int j = 0; j < cnt; j++) {
            int s = __shfl(sv, j, 64);
            float a = __shfl(av, j, 64);
            unsigned int v = hp[(size_t)s * 64 + lane];
            ax += a * blo2f(v);
            ay += a * bhi2f(v);
        }
    }
    float2 b2 = ((const float2*)bias)[lane];
    ((float2*)hagg)[(size_t)w * 64 + lane] = make_float2(ax + b2.x, ay + b2.y);
}

// ---------------- BatchNorm stats / finalize / apply+ELU ----------------
__global__ __launch_bounds__(256) void k_bnstats(const float* __restrict__ hin,
                                                 float* sums, float* sqs, int n) {
    __shared__ float ls[128], lq[128];
    int t = threadIdx.x;
    int c = t & 127, half = t >> 7;
    int r0 = blockIdx.x * 512;
    int rend = min(r0 + 512, n);
    float s = 0.f, q = 0.f;
    for (int r = r0 + half; r < rend; r += 2) {
        float v = hin[(size_t)r * 128 + c];
        s += v; q += v * v;
    }
    if (half) { ls[c] = s; lq[c] = q; }
    __syncthreads();
    if (!half) {
        s += ls[c]; q += lq[c];
        atomicAdd(&sums[c], s);
        atomicAdd(&sqs[c], q);
    }
}

__global__ void k_bnfinal(const float* sums, const float* sqs,
                          const float* gamma, const float* beta,
                          float* sc, float* sh) {
    int c = threadIdx.x;
    float mu = sums[c] / (float)NNODES;
    float var = sqs[c] / (float)NNODES - mu * mu;
    var = fmaxf(var, 0.f);
    float inv = rsqrtf(var + BNEPS);
    float s = gamma[c] * inv;
    sc[c] = s;
    sh[c] = beta[c] - mu * s;
}

__global__ __launch_bounds__(256) void k_bnapply(float* __restrict__ h,
                                                 const float* __restrict__ sc,
                                                 const float* __restrict__ sh) {
    int i = blockIdx.x * 256 + threadIdx.x;   // float4 index, 3.2M total
    int c = (i & 31) * 4;
    float4 v = ((float4*)h)[i];
    float z;
    z = v.x * sc[c + 0] + sh[c + 0]; v.x = z > 0.f ? z : (__expf(z) - 1.f);
    z = v.y * sc[c + 1] + sh[c + 1]; v.y = z > 0.f ? z : (__expf(z) - 1.f);
    z = v.z * sc[c + 2] + sh[c + 2]; v.z = z > 0.f ? z : (__expf(z) - 1.f);
    z = v.w * sc[c + 3] + sh[c + 3]; v.w = z > 0.f ? z : (__expf(z) - 1.f);
    ((float4*)h)[i] = v;
}

// ---------------- output head: out[n,40] = h@Wout + bout ----------------
__global__ __launch_bounds__(256) void k_outgemm(const float* __restrict__ h,
                                                 const float* __restrict__ Wout,
                                                 const float* __restrict__ bout,
                                                 float* __restrict__ out, int n) {
    __shared__ float lwT[40][128];      // transposed Wout
    __shared__ float lh[64][132];       // 64 rows staged
    __shared__ float lb[40];
    int t = threadIdx.x;
    for (int idx = t; idx < 128 * 40; idx += 256) {
        int r = idx / 40, c = idx % 40;
        lwT[c][r] = Wout[idx];
    }
    if (t < 40) lb[t] = bout[t];
    int n0 = blockIdx.x * 64;
#pragma unroll
    for (int j = 0; j < 8; j++) {
        int s = t + j * 256;            // 2048 float4 slots
        int r = s >> 5, c4 = s & 31;
        float4 v = make_float4(0.f, 0.f, 0.f, 0.f);
        if (n0 + r < n) v = ((const float4*)h)[(size_t)(n0 + r) * 32 + c4];
        *(float4*)&lh[r][c4 * 4] = v;
    }
    __syncthreads();
    int nl = t & 63, g = t >> 6;        // 4 groups x 10 cols
    int row = n0 + nl;
    if (row >= n) return;
    float acc[10] = {};
    for (int k = 0; k < 128; k += 4) {
        float4 hv = *(const float4*)&lh[nl][k];
#pragma unroll
        for (int j = 0; j < 10; j++) {
            float4 wv = *(const float4*)&lwT[g * 10 + j][k];
            acc[j] += hv.x * wv.x + hv.y * wv.y + hv.z * wv.z + hv.w * wv.w;
        }
    }
#pragma unroll
    for (int j = 0; j < 10; j++)
        out[(size_t)row * 40 + g * 10 + j] = acc[j] + lb[g * 10 + j];
}

// ---------------- launch ----------------
extern "C" void kernel_launch(void* const* d_in, const int* in_sizes, int n_in,
                              void* d_out, int out_size, void* d_ws, size_t ws_size,
                              hipStream_t stream) {
    const float* x      = (const float*)d_in[0];
    const int*   ei     = (const int*)d_in[1];
    const float* W1     = (const float*)d_in[2];
    const float* a_src1 = (const float*)d_in[3];
    const float* a_dst1 = (const float*)d_in[4];
    const float* b1     = (const float*)d_in[5];
    const float* W2     = (const float*)d_in[6];
    const float* a_src2 = (const float*)d_in[7];
    const float* a_dst2 = (const float*)d_in[8];
    const float* b2     = (const float*)d_in[9];
    const float* gamma  = (const float*)d_in[10];
    const float* beta   = (const float*)d_in[11];
    const float* Wout   = (const float*)d_in[12];
    const float* bout   = (const float*)d_in[13];
    float* out = (float*)d_out;

    char* p = (char*)d_ws;
    auto alloc = [&](size_t bytes) -> void* {
        void* r = (void*)p;
        p += (bytes + 255) & ~(size_t)255;
        return r;
    };
    unsigned short* hB   = (unsigned short*)alloc((size_t)NNODES * 128 * 2);
    float* hagg   = (float*)alloc((size_t)NNODES * 128 * 4);
    float* es     = (float*)alloc((size_t)NNODES * 4);
    float* ed     = (float*)alloc((size_t)NNODES * 4);
    float* alpha  = (float*)alloc((size_t)ET * 4);
    int*   rowptr = (int*)alloc((size_t)(NPAD + 1) * 4);
    int*   wptr   = (int*)alloc((size_t)NNODES * 4);
    int*   cnt    = (int*)alloc((size_t)NPAD * 4);
    int*   srcs   = (int*)alloc((size_t)ET * 4);
    int*   bsum   = (int*)alloc(64 * 4);
    float* bnstat = (float*)alloc(4 * 128 * 4);   // sum1,sq1,sum2,sq2
    float* bnsc   = (float*)alloc(128 * 4);
    float* bnsh   = (float*)alloc(128 * 4);
    unsigned short* WT1 = (unsigned short*)alloc(128 * 128 * 2);
    unsigned short* WT2 = (unsigned short*)alloc(128 * 128 * 2);
    int*   flag   = (int*)alloc(4);

    float* sum1 = bnstat, *sq1 = bnstat + 128, *sum2 = bnstat + 256, *sq2 = bnstat + 384;

    hipMemsetAsync(cnt, 0, (size_t)NPAD * 4, stream);
    hipMemsetAsync(bnstat, 0, 4 * 128 * 4, stream);

    const int EB = (ET + 255) / 256;              // 6641
    k_detect<<<1, 64, 0, stream>>>(ei, flag);
    k_prepW<<<64, 256, 0, stream>>>(W1, W2, WT1, WT2);
    k_hist<<<EB, 256, 0, stream>>>(ei, flag, cnt);
    k_scan1<<<49, 256, 0, stream>>>(cnt, rowptr, bsum);
    k_scan2<<<1, 64, 0, stream>>>(bsum);
    k_scan3<<<NPAD / 256, 256, 0, stream>>>(rowptr, bsum, wptr);
    k_scatter<<<EB, 256, 0, stream>>>(ei, flag, wptr, srcs);

    const int GB = (NNODES + 63) / 64;            // 1563
    const int WB = NNODES / 4;                    // 25000 (exact)
    const int SB = (NNODES + 511) / 512;          // 196

    // ---- layer 1 ----
    k_gemm_mfma<<<GB, 256, 0, stream>>>(x, WT1, hB, NNODES);
    k_scores<<<WB, 256, 0, stream>>>(hB, a_src1, a_dst1, es, ed, NNODES);
    k_alpha<<<WB, 256, 0, stream>>>(srcs, rowptr, es, ed, alpha, NNODES);
    k_wsum<<<WB, 256, 0, stream>>>(hB, srcs, rowptr, alpha, b1, hagg, NNODES);
    k_bnstats<<<SB, 256, 0, stream>>>(hagg, sum1, sq1, NNODES);
    k_bnfinal<<<1, 128, 0, stream>>>(sum1, sq1, gamma, beta, bnsc, bnsh);
    k_bnapply<<<NNODES / 8, 256, 0, stream>>>(hagg, bnsc, bnsh);   // 12500 blocks

    // ---- layer 2 ----
    k_gemm_mfma<<<GB, 256, 0, stream>>>(hagg, WT2, hB, NNODES);
    k_scores<<<WB, 256, 0, stream>>>(hB, a_src2, a_dst2, es, ed, NNODES);
    k_alpha<<<WB, 256, 0, stream>>>(srcs, rowptr, es, ed, alpha, NNODES);
    k_wsum<<<WB, 256, 0, stream>>>(hB, srcs, rowptr, alpha, b2, hagg, NNODES);
    k_bnstats<<<SB, 256, 0, stream>>>(hagg, sum2, sq2, NNODES);
    k_bnfinal<<<1, 128, 0, stream>>>(sum2, sq2, gamma, beta, bnsc, bnsh);
    k_bnapply<<<NNODES / 8, 256, 0, stream>>>(hagg, bnsc, bnsh);

    // ---- head ----
    k_outgemm<<<GB, 256, 0, stream>>>(hagg, Wout, bout, out, NNODES);

    (void)in_sizes; (void)n_in; (void)out_size; (void)ws_size;
}

// Round 3
// 575.443 us; speedup vs baseline: 1.8234x; 1.5491x over previous
//
#include <hip/hip_runtime.h>

#define NNODES 100000
#define NEDGES 1600000
#define ET (NEDGES + NNODES)      // 1,700,000 incl. self loops
#define NBUCK 196                 // ceil(100000/512) buckets of 512 nodes
#define NCLS 40
#define NEG 0.2f
#define BNEPS 1e-5f
#define EPB 16384                 // edges per block, bucket passes
#define NBLK_E ((ET + EPB - 1) / EPB)   // 104

typedef __attribute__((ext_vector_type(8))) short short8;
typedef __attribute__((ext_vector_type(4))) float floatx4;

__device__ __forceinline__ unsigned short f2b(float x) {
    unsigned int u = __float_as_uint(x);
    u += 0x7fff + ((u >> 16) & 1);        // RNE
    return (unsigned short)(u >> 16);
}
__device__ __forceinline__ float b2f(unsigned short u) {
    return __uint_as_float(((unsigned int)u) << 16);
}
__device__ __forceinline__ float blo2f(unsigned int v) {
    return __uint_as_float(v << 16);
}
__device__ __forceinline__ float bhi2f(unsigned int v) {
    return __uint_as_float(v & 0xffff0000u);
}

// ---------------- edge decode (int32 vs int64 hedge) ----------------
__device__ __forceinline__ int edge_src(const int* ei, int e, int w64) {
    if (e >= NEDGES) return e - NEDGES;          // self loop
    return w64 ? ei[2 * e] : ei[e];
}
__device__ __forceinline__ int edge_dst(const int* ei, int e, int w64) {
    if (e >= NEDGES) return e - NEDGES;
    return w64 ? ei[2 * (NEDGES + e)] : ei[NEDGES + e];
}

__global__ void k_detect(const int* ei, int* flag) {
    if (blockIdx.x == 0 && threadIdx.x == 0) {
        int is64 = 1;
        for (int j = 1; j < 16; j += 2)
            if (ei[j] != 0) is64 = 0;
        *flag = is64;
    }
}

// ---------------- W transpose + bf16 convert (once) ----------------
__global__ void k_prepW(const float* __restrict__ W1, const float* __restrict__ W2,
                        unsigned short* __restrict__ WT1, unsigned short* __restrict__ WT2) {
    int t = blockIdx.x * 256 + threadIdx.x;      // 16384 threads
    int k = t >> 7, n = t & 127;
    WT1[n * 128 + k] = f2b(W1[t]);
    WT2[n * 128 + k] = f2b(W2[t]);
}

// ---------------- CSR build: bucket sort by dst ----------------
// Pass A: per-block LDS bucket histogram
__global__ __launch_bounds__(256) void k_bhist(const int* __restrict__ ei,
                                               const int* flag, int* bcnt) {
    __shared__ int lc[256];
    int t = threadIdx.x;
    lc[t] = 0;
    __syncthreads();
    int w64 = *flag;
    int base = blockIdx.x * EPB;
    for (int j = 0; j < EPB / 256; j++) {
        int e = base + j * 256 + t;
        if (e < ET) atomicAdd(&lc[edge_dst(ei, e, w64) >> 9], 1);
    }
    __syncthreads();
    if (t < NBUCK && lc[t]) atomicAdd(&bcnt[t], lc[t]);
}

// Pass B: scan 196 bucket counts
__global__ void k_bscan(const int* __restrict__ bcnt, int* bbase, int* bcur) {
    __shared__ int sh[256];
    int t = threadIdx.x;
    int v = (t < NBUCK) ? bcnt[t] : 0;
    sh[t] = v;
    __syncthreads();
    for (int off = 1; off < 256; off <<= 1) {
        int add = (t >= off) ? sh[t - off] : 0;
        __syncthreads();
        sh[t] += add;
        __syncthreads();
    }
    int excl = sh[t] - v;
    if (t < NBUCK) { bbase[t] = excl; bcur[t] = excl; }
    if (t == NBUCK - 1) bbase[NBUCK] = sh[t];
}

// Pass C: partition (src,dst) pairs into bucket regions
__global__ __launch_bounds__(256) void k_bscatter(const int* __restrict__ ei,
                                                  const int* flag, int* bcur,
                                                  int2* __restrict__ pairs) {
    __shared__ int lc[256];
    __shared__ int lbase[256];
    int t = threadIdx.x;
    lc[t] = 0;
    __syncthreads();
    int w64 = *flag;
    int base = blockIdx.x * EPB;
    for (int j = 0; j < EPB / 256; j++) {
        int e = base + j * 256 + t;
        if (e < ET) atomicAdd(&lc[edge_dst(ei, e, w64) >> 9], 1);
    }
    __syncthreads();
    if (t < NBUCK && lc[t]) lbase[t] = atomicAdd(&bcur[t], lc[t]);
    __syncthreads();
    for (int j = 0; j < EPB / 256; j++) {
        int e = base + j * 256 + t;
        if (e < ET) {
            int src = edge_src(ei, e, w64);
            int dst = edge_dst(ei, e, w64);
            int pos = atomicAdd(&lbase[dst >> 9], 1);
            pairs[pos] = make_int2(src, dst);
        }
    }
}

// Pass D: per-bucket counting sort over 512 local nodes -> rowptr + srcs
__global__ __launch_bounds__(256) void k_bsort(const int2* __restrict__ pairs,
                                               const int* __restrict__ bbase,
                                               int* __restrict__ rowptr,
                                               int* __restrict__ srcs) {
    __shared__ int ncnt[512];
    __shared__ int nbase[512];
    __shared__ int stmp[256];
    int b = blockIdx.x, t = threadIdx.x;
    ncnt[t] = 0; ncnt[t + 256] = 0;
    __syncthreads();
    int s0 = bbase[b], s1 = bbase[b + 1];
    for (int i = s0 + t; i < s1; i += 256)
        atomicAdd(&ncnt[pairs[i].y & 511], 1);
    __syncthreads();
    int c0 = ncnt[2 * t], c1 = ncnt[2 * t + 1];
    int s = c0 + c1;
    stmp[t] = s;
    __syncthreads();
    for (int off = 1; off < 256; off <<= 1) {
        int add = (t >= off) ? stmp[t - off] : 0;
        __syncthreads();
        stmp[t] += add;
        __syncthreads();
    }
    int excl = stmp[t] - s;
    nbase[2 * t] = excl;
    nbase[2 * t + 1] = excl + c0;
    __syncthreads();
    for (int l = t; l < 512; l += 256) {
        int node = b * 512 + l;
        if (node <= NNODES) rowptr[node] = s0 + nbase[l];
        ncnt[l] = nbase[l];            // becomes cursor
    }
    __syncthreads();
    for (int i = s0 + t; i < s1; i += 256) {
        int2 pr = pairs[i];
        int off = atomicAdd(&ncnt[pr.y & 511], 1);
        srcs[s0 + off] = pr.x;
    }
}

// ---------------- MFMA GEMM (+opt BN/ELU on A) + fused scores ----------------
template<bool BN>
__global__ __launch_bounds__(256) void k_gemm_mfma(const float* __restrict__ A,
        const unsigned short* __restrict__ WTg,
        const float* __restrict__ bnsc, const float* __restrict__ bnsh,
        const float* __restrict__ a_s, const float* __restrict__ a_d,
        float* __restrict__ es, float* __restrict__ ed,
        unsigned short* __restrict__ hB, int n) {
    __shared__ unsigned short lA[64][136];
    __shared__ unsigned short lW[128][136];
    __shared__ float las[128], lad[128];
    int t = threadIdx.x;
    int row0 = blockIdx.x * 64;
    if (t < 128) { las[t] = a_s[t]; lad[t] = a_d[t]; }

    const uint4* wt4 = (const uint4*)WTg;
#pragma unroll
    for (int j = 0; j < 8; j++) {
        int idx = t + j * 256;
        *(uint4*)&lW[idx >> 4][(idx & 15) * 8] = wt4[idx];
    }
#pragma unroll
    for (int j = 0; j < 8; j++) {
        int idx = t + j * 256;
        int r = idx >> 5, c4 = idx & 31;
        float4 v = make_float4(0.f, 0.f, 0.f, 0.f);
        if (row0 + r < n) v = ((const float4*)A)[(size_t)(row0 + r) * 32 + c4];
        if (BN) {
            float4 s4 = ((const float4*)bnsc)[c4];
            float4 h4 = ((const float4*)bnsh)[c4];
            v.x = fmaf(v.x, s4.x, h4.x); v.x = v.x > 0.f ? v.x : __expf(v.x) - 1.f;
            v.y = fmaf(v.y, s4.y, h4.y); v.y = v.y > 0.f ? v.y : __expf(v.y) - 1.f;
            v.z = fmaf(v.z, s4.z, h4.z); v.z = v.z > 0.f ? v.z : __expf(v.z) - 1.f;
            v.w = fmaf(v.w, s4.w, h4.w); v.w = v.w > 0.f ? v.w : __expf(v.w) - 1.f;
        }
        ushort4 u;
        u.x = f2b(v.x); u.y = f2b(v.y); u.z = f2b(v.z); u.w = f2b(v.w);
        *(ushort4*)&lA[r][c4 * 4] = u;
    }
    __syncthreads();

    int w = t >> 6, lane = t & 63;
    int m = lane & 15, q = lane >> 4;
    int arow = w * 16 + m;
    floatx4 acc[8];
#pragma unroll
    for (int ct = 0; ct < 8; ct++) acc[ct] = (floatx4)0.0f;

#pragma unroll
    for (int kt = 0; kt < 4; kt++) {
        int kb = kt * 32 + q * 8;
        short8 af = *(const short8*)&lA[arow][kb];
#pragma unroll
        for (int ct = 0; ct < 8; ct++) {
            short8 bf = *(const short8*)&lW[ct * 16 + m][kb];
            acc[ct] = __builtin_amdgcn_mfma_f32_16x16x32_bf16(af, bf, acc[ct], 0, 0, 0);
        }
    }

    // epilogue: frags -> lA (wave-private rows) -> coalesced store
#pragma unroll
    for (int ct = 0; ct < 8; ct++)
#pragma unroll
        for (int r = 0; r < 4; r++)
            lA[w * 16 + q * 4 + r][ct * 16 + m] = f2b(acc[ct][r]);
#pragma unroll
    for (int j = 0; j < 4; j++) {
        int idx = lane + j * 64;
        int r = idx >> 4, seg = idx & 15;
        int grow = row0 + w * 16 + r;
        if (grow < n) {
            uint4 v = *(const uint4*)&lA[w * 16 + r][seg * 8];
            ((uint4*)hB)[(size_t)grow * 16 + seg] = v;
        }
    }
    __syncthreads();
    // fused attention scores: 4 threads per row, 32 chans each
    int r = t >> 2, q4 = t & 3;
    float s1 = 0.f, s2 = 0.f;
#pragma unroll
    for (int k = 0; k < 32; k++) {
        int c = q4 * 32 + k;
        float v = b2f(lA[r][c]);
        s1 += v * las[c];
        s2 += v * lad[c];
    }
    s1 += __shfl_xor(s1, 1, 64); s1 += __shfl_xor(s1, 2, 64);
    s2 += __shfl_xor(s2, 1, 64); s2 += __shfl_xor(s2, 2, 64);
    if (q4 == 0 && row0 + r < n) { es[row0 + r] = s1; ed[row0 + r] = s2; }
}

// ---------------- fused softmax + weighted gather (wave per node) ----------------
__global__ __launch_bounds__(256) void k_attn(const unsigned short* __restrict__ hB,
                                              const int* __restrict__ srcs,
                                              const int* __restrict__ rowptr,
                                              const float* __restrict__ es,
                                              const float* __restrict__ ed,
                                              const float* __restrict__ bias,
                                              float* __restrict__ hagg, int n) {
    int w = (blockIdx.x * 256 + threadIdx.x) >> 6;
    if (w >= n) return;
    int lane = threadIdx.x & 63;
    int start = rowptr[w], end = rowptr[w + 1];
    float edv = ed[w];

    // pass 1: max of es[src] (leaky is monotone; apply after)
    float mx = -3.0e38f;
    for (int i = start + lane; i < end; i += 64)
        mx = fmaxf(mx, es[srcs[i]]);
    for (int off = 32; off; off >>= 1) mx = fmaxf(mx, __shfl_xor(mx, off, 64));
    float mfull = mx + edv;
    mfull = mfull > 0.f ? mfull : NEG * mfull;

    // pass 2: p per lane, vectorized 16B gather (4 edges per round)
    int l16 = lane & 15, g = lane >> 4;
    const uint4* hp4 = (const uint4*)hB;
    float acc[8] = {};
    float den = 0.f;
    for (int chunk = start; chunk < end; chunk += 64) {
        int i = chunk + lane;
        int sv = 0; float pv = 0.f;
        if (i < end) {
            sv = srcs[i];
            float e = es[sv] + edv;
            e = e > 0.f ? e : NEG * e;
            pv = __expf(e - mfull);
            den += pv;
        }
        int cnt = min(64, end - chunk);
        for (int j = 0; j < cnt; j += 8) {
            int j0 = j + g, j1 = j + 4 + g;          // <= 63 always
            int   s0 = __shfl(sv, j0, 64);
            float p0 = __shfl(pv, j0, 64);
            int   s1 = __shfl(sv, j1, 64);
            float p1 = __shfl(pv, j1, 64);
            uint4 h0 = hp4[(size_t)s0 * 16 + l16];
            uint4 h1 = hp4[(size_t)s1 * 16 + l16];
            acc[0] += p0 * blo2f(h0.x); acc[1] += p0 * bhi2f(h0.x);
            acc[2] += p0 * blo2f(h0.y); acc[3] += p0 * bhi2f(h0.y);
            acc[4] += p0 * blo2f(h0.z); acc[5] += p0 * bhi2f(h0.z);
            acc[6] += p0 * blo2f(h0.w); acc[7] += p0 * bhi2f(h0.w);
            acc[0] += p1 * blo2f(h1.x); acc[1] += p1 * bhi2f(h1.x);
            acc[2] += p1 * blo2f(h1.y); acc[3] += p1 * bhi2f(h1.y);
            acc[4] += p1 * blo2f(h1.z); acc[5] += p1 * bhi2f(h1.z);
            acc[6] += p1 * blo2f(h1.w); acc[7] += p1 * bhi2f(h1.w);
        }
    }
    for (int off = 32; off; off >>= 1) den += __shfl_xor(den, off, 64);
#pragma unroll
    for (int k = 0; k < 8; k++) {
        acc[k] += __shfl_xor(acc[k], 16, 64);
        acc[k] += __shfl_xor(acc[k], 32, 64);
    }
    if (g == 0) {
        float inv = 1.f / den;
        float4 b0 = ((const float4*)bias)[l16 * 2];
        float4 b1 = ((const float4*)bias)[l16 * 2 + 1];
        float4 o0 = make_float4(fmaf(acc[0], inv, b0.x), fmaf(acc[1], inv, b0.y),
                                fmaf(acc[2], inv, b0.z), fmaf(acc[3], inv, b0.w));
        float4 o1 = make_float4(fmaf(acc[4], inv, b1.x), fmaf(acc[5], inv, b1.y),
                                fmaf(acc[6], inv, b1.z), fmaf(acc[7], inv, b1.w));
        ((float4*)hagg)[(size_t)w * 32 + l16 * 2]     = o0;
        ((float4*)hagg)[(size_t)w * 32 + l16 * 2 + 1] = o1;
    }
}

// ---------------- BatchNorm stats / finalize ----------------
__global__ __launch_bounds__(256) void k_bnstats(const float* __restrict__ hin,
                                                 float* sums, float* sqs, int n) {
    __shared__ float ls[128], lq[128];
    int t = threadIdx.x;
    int c = t & 127, half = t >> 7;
    int r0 = blockIdx.x * 512;
    int rend = min(r0 + 512, n);
    float s = 0.f, q = 0.f;
    for (int r = r0 + half; r < rend; r += 2) {
        float v = hin[(size_t)r * 128 + c];
        s += v; q += v * v;
    }
    if (half) { ls[c] = s; lq[c] = q; }
    __syncthreads();
    if (!half) {
        s += ls[c]; q += lq[c];
        atomicAdd(&sums[c], s);
        atomicAdd(&sqs[c], q);
    }
}

__global__ void k_bnfinal(const float* sums, const float* sqs,
                          const float* gamma, const float* beta,
                          float* sc, float* sh) {
    int c = threadIdx.x;
    float mu = sums[c] / (float)NNODES;
    float var = sqs[c] / (float)NNODES - mu * mu;
    var = fmaxf(var, 0.f);
    float inv = rsqrtf(var + BNEPS);
    float s = gamma[c] * inv;
    sc[c] = s;
    sh[c] = beta[c] - mu * s;
}

// ---------------- output head with fused BN+ELU on load ----------------
__global__ __launch_bounds__(256) void k_outgemm(const float* __restrict__ h,
                                                 const float* __restrict__ bnsc,
                                                 const float* __restrict__ bnsh,
                                                 const float* __restrict__ Wout,
                                                 const float* __restrict__ bout,
                                                 float* __restrict__ out, int n) {
    __shared__ float lwT[40][128];
    __shared__ float lh[64][132];
    __shared__ float lb[40];
    int t = threadIdx.x;
    for (int idx = t; idx < 128 * 40; idx += 256) {
        int r = idx / 40, c = idx % 40;
        lwT[c][r] = Wout[idx];
    }
    if (t < 40) lb[t] = bout[t];
    int n0 = blockIdx.x * 64;
#pragma unroll
    for (int j = 0; j < 8; j++) {
        int s = t + j * 256;
        int r = s >> 5, c4 = s & 31;
        float4 v = make_float4(0.f, 0.f, 0.f, 0.f);
        if (n0 + r < n) v = ((const float4*)h)[(size_t)(n0 + r) * 32 + c4];
        float4 s4 = ((const float4*)bnsc)[c4];
        float4 h4 = ((const float4*)bnsh)[c4];
        v.x = fmaf(v.x, s4.x, h4.x); v.x = v.x > 0.f ? v.x : __expf(v.x) - 1.f;
        v.y = fmaf(v.y, s4.y, h4.y); v.y = v.y > 0.f ? v.y : __expf(v.y) - 1.f;
        v.z = fmaf(v.z, s4.z, h4.z); v.z = v.z > 0.f ? v.z : __expf(v.z) - 1.f;
        v.w = fmaf(v.w, s4.w, h4.w); v.w = v.w > 0.f ? v.w : __expf(v.w) - 1.f;
        *(float4*)&lh[r][c4 * 4] = v;
    }
    __syncthreads();
    int nl = t & 63, g = t >> 6;
    int row = n0 + nl;
    if (row >= n) return;
    float acc[10] = {};
    for (int k = 0; k < 128; k += 4) {
        float4 hv = *(const float4*)&lh[nl][k];
#pragma unroll
        for (int j = 0; j < 10; j++) {
            float4 wv = *(const float4*)&lwT[g * 10 + j][k];
            acc[j] += hv.x * wv.x + hv.y * wv.y + hv.z * wv.z + hv.w * wv.w;
        }
    }
#pragma unroll
    for (int j = 0; j < 10; j++)
        out[(size_t)row * 40 + g * 10 + j] = acc[j] + lb[g * 10 + j];
}

// ---------------- launch ----------------
extern "C" void kernel_launch(void* const* d_in, const int* in_sizes, int n_in,
                              void* d_out, int out_size, void* d_ws, size_t ws_size,
                              hipStream_t stream) {
    const float* x      = (const float*)d_in[0];
    const int*   ei     = (const int*)d_in[1];
    const float* W1     = (const float*)d_in[2];
    const float* a_src1 = (const float*)d_in[3];
    const float* a_dst1 = (const float*)d_in[4];
    const float* b1     = (const float*)d_in[5];
    const float* W2     = (const float*)d_in[6];
    const float* a_src2 = (const float*)d_in[7];
    const float* a_dst2 = (const float*)d_in[8];
    const float* b2     = (const float*)d_in[9];
    const float* gamma  = (const float*)d_in[10];
    const float* beta   = (const float*)d_in[11];
    const float* Wout   = (const float*)d_in[12];
    const float* bout   = (const float*)d_in[13];
    float* out = (float*)d_out;

    char* p = (char*)d_ws;
    auto alloc = [&](size_t bytes) -> void* {
        void* r = (void*)p;
        p += (bytes + 255) & ~(size_t)255;
        return r;
    };
    unsigned short* hB = (unsigned short*)alloc((size_t)NNODES * 128 * 2);
    float* hagg   = (float*)alloc((size_t)NNODES * 128 * 4);
    float* es     = (float*)alloc((size_t)NNODES * 4);
    float* ed     = (float*)alloc((size_t)NNODES * 4);
    int2*  pairs  = (int2*)alloc((size_t)ET * 8);
    int*   srcs   = (int*)alloc((size_t)ET * 4);
    int*   rowptr = (int*)alloc((size_t)(NNODES + 1) * 4);
    int*   bcnt   = (int*)alloc(256 * 4);
    int*   bbase  = (int*)alloc(256 * 4);
    int*   bcur   = (int*)alloc(256 * 4);
    float* bnstat = (float*)alloc(4 * 128 * 4);
    float* bnsc   = (float*)alloc(128 * 4);
    float* bnsh   = (float*)alloc(128 * 4);
    unsigned short* WT1 = (unsigned short*)alloc(128 * 128 * 2);
    unsigned short* WT2 = (unsigned short*)alloc(128 * 128 * 2);
    int*   flag   = (int*)alloc(4);

    float* sum1 = bnstat, *sq1 = bnstat + 128, *sum2 = bnstat + 256, *sq2 = bnstat + 384;

    hipMemsetAsync(bcnt, 0, 256 * 4, stream);
    hipMemsetAsync(bnstat, 0, 4 * 128 * 4, stream);

    k_detect<<<1, 64, 0, stream>>>(ei, flag);
    k_prepW<<<64, 256, 0, stream>>>(W1, W2, WT1, WT2);
    k_bhist<<<NBLK_E, 256, 0, stream>>>(ei, flag, bcnt);
    k_bscan<<<1, 256, 0, stream>>>(bcnt, bbase, bcur);
    k_bscatter<<<NBLK_E, 256, 0, stream>>>(ei, flag, bcur, pairs);
    k_bsort<<<NBUCK, 256, 0, stream>>>(pairs, bbase, rowptr, srcs);

    const int GB = (NNODES + 63) / 64;            // 1563
    const int WB = NNODES / 4;                    // 25000
    const int SB = (NNODES + 511) / 512;          // 196

    // ---- layer 1 ----
    k_gemm_mfma<false><<<GB, 256, 0, stream>>>(x, WT1, nullptr, nullptr,
                                               a_src1, a_dst1, es, ed, hB, NNODES);
    k_attn<<<WB, 256, 0, stream>>>(hB, srcs, rowptr, es, ed, b1, hagg, NNODES);
    k_bnstats<<<SB, 256, 0, stream>>>(hagg, sum1, sq1, NNODES);
    k_bnfinal<<<1, 128, 0, stream>>>(sum1, sq1, gamma, beta, bnsc, bnsh);

    // ---- layer 2 (BN+ELU fused into A-staging) ----
    k_gemm_mfma<true><<<GB, 256, 0, stream>>>(hagg, WT2, bnsc, bnsh,
                                              a_src2, a_dst2, es, ed, hB, NNODES);
    k_attn<<<WB, 256, 0, stream>>>(hB, srcs, rowptr, es, ed, b2, hagg, NNODES);
    k_bnstats<<<SB, 256, 0, stream>>>(hagg, sum2, sq2, NNODES);
    k_bnfinal<<<1, 128, 0, stream>>>(sum2, sq2, gamma, beta, bnsc, bnsh);

    // ---- head (BN+ELU fused into staging) ----
    k_outgemm<<<GB, 256, 0, stream>>>(hagg, bnsc, bnsh, Wout, bout, out, NNODES);

    (void)in_sizes; (void)n_in; (void)out_size; (void)ws_size;
}

// Round 4
// 491.675 us; speedup vs baseline: 2.1340x; 1.1704x over previous
//
#include <hip/hip_runtime.h>

#define NNODES 100000
#define NEDGES 1600000
#define ET (NEDGES + NNODES)      // 1,700,000 incl. self loops
#define NBUCK 196                 // ceil(100000/512) buckets of 512 nodes
#define NEG 0.2f
#define BNEPS 1e-5f
#define EPB 16384                 // edges per block, bucket passes
#define NBLK_E ((ET + EPB - 1) / EPB)   // 104

typedef __attribute__((ext_vector_type(8))) short short8;
typedef __attribute__((ext_vector_type(4))) float floatx4;
typedef __attribute__((ext_vector_type(2))) float floatx2;

__device__ __forceinline__ unsigned short f2b(float x) {
    unsigned int u = __float_as_uint(x);
    u += 0x7fff + ((u >> 16) & 1);        // RNE
    return (unsigned short)(u >> 16);
}
__device__ __forceinline__ float b2f(unsigned short u) {
    return __uint_as_float(((unsigned int)u) << 16);
}
__device__ __forceinline__ float blo2f(unsigned int v) {
    return __uint_as_float(v << 16);
}
__device__ __forceinline__ float bhi2f(unsigned int v) {
    return __uint_as_float(v & 0xffff0000u);
}
__device__ __forceinline__ floatx2 u2f2(unsigned int v) {
    floatx2 r;
    r.x = __uint_as_float(v << 16);
    r.y = __uint_as_float(v & 0xffff0000u);
    return r;
}

// ---------------- edge decode (int32 vs int64 hedge) ----------------
__device__ __forceinline__ int edge_src(const int* ei, int e, int w64) {
    if (e >= NEDGES) return e - NEDGES;          // self loop
    return w64 ? ei[2 * e] : ei[e];
}
__device__ __forceinline__ int edge_dst(const int* ei, int e, int w64) {
    if (e >= NEDGES) return e - NEDGES;
    return w64 ? ei[2 * (NEDGES + e)] : ei[NEDGES + e];
}

// ---------------- prep: dtype detect + W transpose to bf16 ----------------
__global__ void k_prep(const float* __restrict__ W1, const float* __restrict__ W2,
                       unsigned short* __restrict__ WT1, unsigned short* __restrict__ WT2,
                       const int* ei, int* flag) {
    int t = blockIdx.x * 256 + threadIdx.x;      // 16384 threads
    if (t == 0) {
        int is64 = 1;
        for (int j = 1; j < 16; j += 2)
            if (ei[j] != 0) is64 = 0;
        *flag = is64;
    }
    int k = t >> 7, n = t & 127;
    WT1[n * 128 + k] = f2b(W1[t]);
    WT2[n * 128 + k] = f2b(W2[t]);
}

// ---------------- CSR build: bucket sort by dst ----------------
__global__ __launch_bounds__(256) void k_bhist(const int* __restrict__ ei,
                                               const int* flag, int* bcnt) {
    __shared__ int lc[256];
    int t = threadIdx.x;
    lc[t] = 0;
    __syncthreads();
    int w64 = *flag;
    int base = blockIdx.x * EPB;
    for (int j = 0; j < EPB / 256; j++) {
        int e = base + j * 256 + t;
        if (e < ET) atomicAdd(&lc[edge_dst(ei, e, w64) >> 9], 1);
    }
    __syncthreads();
    if (t < NBUCK && lc[t]) atomicAdd(&bcnt[t], lc[t]);
}

__global__ void k_bscan(const int* __restrict__ bcnt, int* bbase, int* bcur) {
    __shared__ int sh[256];
    int t = threadIdx.x;
    int v = (t < NBUCK) ? bcnt[t] : 0;
    sh[t] = v;
    __syncthreads();
    for (int off = 1; off < 256; off <<= 1) {
        int add = (t >= off) ? sh[t - off] : 0;
        __syncthreads();
        sh[t] += add;
        __syncthreads();
    }
    int excl = sh[t] - v;
    if (t < NBUCK) { bbase[t] = excl; bcur[t] = excl; }
    if (t == NBUCK - 1) bbase[NBUCK] = sh[t];
}

// pairs packed: (src << 9) | (dst & 511); src < 2^17
__global__ __launch_bounds__(256) void k_bscatter(const int* __restrict__ ei,
                                                  const int* flag, int* bcur,
                                                  int* __restrict__ pairs) {
    __shared__ int lc[256];
    __shared__ int lbase[256];
    int t = threadIdx.x;
    lc[t] = 0;
    __syncthreads();
    int w64 = *flag;
    int base = blockIdx.x * EPB;
    for (int j = 0; j < EPB / 256; j++) {
        int e = base + j * 256 + t;
        if (e < ET) atomicAdd(&lc[edge_dst(ei, e, w64) >> 9], 1);
    }
    __syncthreads();
    if (t < NBUCK && lc[t]) lbase[t] = atomicAdd(&bcur[t], lc[t]);
    __syncthreads();
    for (int j = 0; j < EPB / 256; j++) {
        int e = base + j * 256 + t;
        if (e < ET) {
            int src = edge_src(ei, e, w64);
            int dst = edge_dst(ei, e, w64);
            int pos = atomicAdd(&lbase[dst >> 9], 1);
            pairs[pos] = (src << 9) | (dst & 511);
        }
    }
}

__global__ __launch_bounds__(256) void k_bsort(const int* __restrict__ pairs,
                                               const int* __restrict__ bbase,
                                               int* __restrict__ rowptr,
                                               int* __restrict__ srcs) {
    __shared__ int ncnt[512];
    __shared__ int nbase[512];
    __shared__ int stmp[256];
    int b = blockIdx.x, t = threadIdx.x;
    ncnt[t] = 0; ncnt[t + 256] = 0;
    __syncthreads();
    int s0 = bbase[b], s1 = bbase[b + 1];
    for (int i = s0 + t; i < s1; i += 256)
        atomicAdd(&ncnt[pairs[i] & 511], 1);
    __syncthreads();
    int c0 = ncnt[2 * t], c1 = ncnt[2 * t + 1];
    int s = c0 + c1;
    stmp[t] = s;
    __syncthreads();
    for (int off = 1; off < 256; off <<= 1) {
        int add = (t >= off) ? stmp[t - off] : 0;
        __syncthreads();
        stmp[t] += add;
        __syncthreads();
    }
    int excl = stmp[t] - s;
    nbase[2 * t] = excl;
    nbase[2 * t + 1] = excl + c0;
    __syncthreads();
    for (int l = t; l < 512; l += 256) {
        int node = b * 512 + l;
        if (node <= NNODES) rowptr[node] = s0 + nbase[l];
        ncnt[l] = nbase[l];            // becomes cursor
    }
    __syncthreads();
    for (int i = s0 + t; i < s1; i += 256) {
        int pr = pairs[i];
        int off = atomicAdd(&ncnt[pr & 511], 1);
        srcs[s0 + off] = ((unsigned int)pr) >> 9;
    }
}

// ---------------- MFMA GEMM (+in-block BN/ELU on bf16 A) + fused scores ----------------
template<bool BN>
__global__ __launch_bounds__(256) void k_gemm(const void* __restrict__ Ain,
        const unsigned short* __restrict__ WTg,
        const float* __restrict__ sums, const float* __restrict__ sqs,
        const float* __restrict__ gamma, const float* __restrict__ beta,
        const float* __restrict__ a_s, const float* __restrict__ a_d,
        float* __restrict__ es, float* __restrict__ ed,
        unsigned short* __restrict__ hB, int n) {
    __shared__ unsigned short lA[64][136];
    __shared__ unsigned short lW[128][136];
    __shared__ float las[128], lad[128];
    __shared__ float lsc[128], lsh[128];
    int t = threadIdx.x;
    int row0 = blockIdx.x * 64;
    if (t < 128) { las[t] = a_s[t]; lad[t] = a_d[t]; }
    if (BN && t < 128) {
        float mu = sums[t] * (1.f / NNODES);
        float var = fmaxf(sqs[t] * (1.f / NNODES) - mu * mu, 0.f);
        float s = gamma[t] * rsqrtf(var + BNEPS);
        lsc[t] = s;
        lsh[t] = beta[t] - mu * s;
    }

    const uint4* wt4 = (const uint4*)WTg;
#pragma unroll
    for (int j = 0; j < 8; j++) {
        int idx = t + j * 256;
        *(uint4*)&lW[idx >> 4][(idx & 15) * 8] = wt4[idx];
    }
    if (BN) __syncthreads();   // lsc/lsh visible before A staging

    if (BN) {
        const uint4* Ab = (const uint4*)Ain;   // bf16 rows, 16 uint4 each
#pragma unroll
        for (int j = 0; j < 4; j++) {
            int idx = t + j * 256;
            int r = idx >> 4, seg = idx & 15;
            uint4 v = make_uint4(0, 0, 0, 0);
            if (row0 + r < n) v = Ab[(size_t)(row0 + r) * 16 + seg];
            float f[8];
            f[0] = blo2f(v.x); f[1] = bhi2f(v.x);
            f[2] = blo2f(v.y); f[3] = bhi2f(v.y);
            f[4] = blo2f(v.z); f[5] = bhi2f(v.z);
            f[6] = blo2f(v.w); f[7] = bhi2f(v.w);
            ushort4 u0, u1;
            unsigned short us[8];
#pragma unroll
            for (int k = 0; k < 8; k++) {
                int c = seg * 8 + k;
                float z = fmaf(f[k], lsc[c], lsh[c]);
                z = z > 0.f ? z : __expf(z) - 1.f;
                us[k] = f2b(z);
            }
            u0.x = us[0]; u0.y = us[1]; u0.z = us[2]; u0.w = us[3];
            u1.x = us[4]; u1.y = us[5]; u1.z = us[6]; u1.w = us[7];
            *(ushort4*)&lA[r][seg * 8] = u0;
            *(ushort4*)&lA[r][seg * 8 + 4] = u1;
        }
    } else {
        const float* Af = (const float*)Ain;
#pragma unroll
        for (int j = 0; j < 8; j++) {
            int idx = t + j * 256;
            int r = idx >> 5, c4 = idx & 31;
            float4 v = make_float4(0.f, 0.f, 0.f, 0.f);
            if (row0 + r < n) v = ((const float4*)Af)[(size_t)(row0 + r) * 32 + c4];
            ushort4 u;
            u.x = f2b(v.x); u.y = f2b(v.y); u.z = f2b(v.z); u.w = f2b(v.w);
            *(ushort4*)&lA[r][c4 * 4] = u;
        }
    }
    __syncthreads();

    int w = t >> 6, lane = t & 63;
    int m = lane & 15, q = lane >> 4;
    int arow = w * 16 + m;
    floatx4 acc[8];
#pragma unroll
    for (int ct = 0; ct < 8; ct++) acc[ct] = (floatx4)0.0f;

#pragma unroll
    for (int kt = 0; kt < 4; kt++) {
        int kb = kt * 32 + q * 8;
        short8 af = *(const short8*)&lA[arow][kb];
#pragma unroll
        for (int ct = 0; ct < 8; ct++) {
            short8 bf = *(const short8*)&lW[ct * 16 + m][kb];
            acc[ct] = __builtin_amdgcn_mfma_f32_16x16x32_bf16(af, bf, acc[ct], 0, 0, 0);
        }
    }

    __syncthreads();   // done reading lA as input; about to overwrite with C tile
#pragma unroll
    for (int ct = 0; ct < 8; ct++)
#pragma unroll
        for (int r = 0; r < 4; r++)
            lA[w * 16 + q * 4 + r][ct * 16 + m] = f2b(acc[ct][r]);
#pragma unroll
    for (int j = 0; j < 4; j++) {
        int idx = lane + j * 64;
        int r = idx >> 4, seg = idx & 15;
        int grow = row0 + w * 16 + r;
        if (grow < n) {
            uint4 v = *(const uint4*)&lA[w * 16 + r][seg * 8];
            ((uint4*)hB)[(size_t)grow * 16 + seg] = v;
        }
    }
    __syncthreads();
    // fused attention scores: 4 threads per row, 32 chans each
    int r = t >> 2, q4 = t & 3;
    float s1 = 0.f, s2 = 0.f;
#pragma unroll
    for (int k = 0; k < 32; k++) {
        int c = q4 * 32 + k;
        float v = b2f(lA[r][c]);
        s1 += v * las[c];
        s2 += v * lad[c];
    }
    s1 += __shfl_xor(s1, 1, 64); s1 += __shfl_xor(s1, 2, 64);
    s2 += __shfl_xor(s2, 1, 64); s2 += __shfl_xor(s2, 2, 64);
    if (q4 == 0 && row0 + r < n) { es[row0 + r] = s1; ed[row0 + r] = s2; }
}

// ---------------- fused softmax + weighted gather (half-wave per node) ----------------
// one pass: no max subtraction (scores bounded |e| << 88, exp safe in fp32;
// alpha = p/den is shift-invariant so result identical)
__global__ __launch_bounds__(256) void k_attn(const unsigned short* __restrict__ hB,
                                              const int* __restrict__ srcs,
                                              const int* __restrict__ rowptr,
                                              const float* __restrict__ es,
                                              const float* __restrict__ ed,
                                              const float* __restrict__ bias,
                                              unsigned short* __restrict__ haggB, int n) {
    int w = (blockIdx.x * 256 + threadIdx.x) >> 5;   // node per half-wave
    if (w >= n) return;
    int lane32 = threadIdx.x & 31;
    int g = lane32 >> 4, l16 = lane32 & 15;
    int base = threadIdx.x & 32;                     // this half's lane offset in wave
    int start = rowptr[w], end = rowptr[w + 1];
    float edv = ed[w];
    const uint4* hp4 = (const uint4*)hB;
    floatx2 a0 = {0.f, 0.f}, a1 = {0.f, 0.f}, a2 = {0.f, 0.f}, a3 = {0.f, 0.f};
    float den = 0.f;

    for (int chunk = start; chunk < end; chunk += 32) {
        int i = chunk + lane32;
        int sv = 0; float pv = 0.f;
        if (i < end) {
            sv = srcs[i];
            float e = es[sv] + edv;
            e = e > 0.f ? e : NEG * e;
            pv = __expf(e);
            den += pv;
        }
        int cnt = min(32, end - chunk);
        for (int j = 0; j < cnt; j += 4) {           // 2 groups x 2 edges per iter
            int   s0 = __shfl(sv, base + j + g, 64);
            float p0 = __shfl(pv, base + j + g, 64);
            int   s1 = __shfl(sv, base + j + 2 + g, 64);
            float p1 = __shfl(pv, base + j + 2 + g, 64);
            if (p0 != 0.f) {
                uint4 h0 = hp4[(size_t)s0 * 16 + l16];
                floatx2 P = {p0, p0};
                a0 += P * u2f2(h0.x); a1 += P * u2f2(h0.y);
                a2 += P * u2f2(h0.z); a3 += P * u2f2(h0.w);
            }
            if (p1 != 0.f) {
                uint4 h1 = hp4[(size_t)s1 * 16 + l16];
                floatx2 P = {p1, p1};
                a0 += P * u2f2(h1.x); a1 += P * u2f2(h1.y);
                a2 += P * u2f2(h1.z); a3 += P * u2f2(h1.w);
            }
        }
    }
    den += __shfl_xor(den, 1, 64);  den += __shfl_xor(den, 2, 64);
    den += __shfl_xor(den, 4, 64);  den += __shfl_xor(den, 8, 64);
    den += __shfl_xor(den, 16, 64);
    a0.x += __shfl_xor(a0.x, 16, 64); a0.y += __shfl_xor(a0.y, 16, 64);
    a1.x += __shfl_xor(a1.x, 16, 64); a1.y += __shfl_xor(a1.y, 16, 64);
    a2.x += __shfl_xor(a2.x, 16, 64); a2.y += __shfl_xor(a2.y, 16, 64);
    a3.x += __shfl_xor(a3.x, 16, 64); a3.y += __shfl_xor(a3.y, 16, 64);
    if (g == 0) {
        float inv = 1.f / den;                       // den > 0: self loop guaranteed
        const float2* b2 = (const float2*)bias;
        float2 c0 = b2[l16 * 4 + 0], c1 = b2[l16 * 4 + 1];
        float2 c2 = b2[l16 * 4 + 2], c3 = b2[l16 * 4 + 3];
        uint4 o;
        o.x = (unsigned int)f2b(fmaf(a0.x, inv, c0.x)) |
              ((unsigned int)f2b(fmaf(a0.y, inv, c0.y)) << 16);
        o.y = (unsigned int)f2b(fmaf(a1.x, inv, c1.x)) |
              ((unsigned int)f2b(fmaf(a1.y, inv, c1.y)) << 16);
        o.z = (unsigned int)f2b(fmaf(a2.x, inv, c2.x)) |
              ((unsigned int)f2b(fmaf(a2.y, inv, c2.y)) << 16);
        o.w = (unsigned int)f2b(fmaf(a3.x, inv, c3.x)) |
              ((unsigned int)f2b(fmaf(a3.y, inv, c3.y)) << 16);
        ((uint4*)haggB)[(size_t)w * 16 + l16] = o;
    }
}

// ---------------- BatchNorm stats from bf16 hagg ----------------
__global__ __launch_bounds__(256) void k_bnstats(const unsigned short* __restrict__ hin,
                                                 float* sums, float* sqs, int n) {
    __shared__ float red[4][256];
    int t = threadIdx.x;
    int c2 = t & 63, quarter = t >> 6;
    int r0 = blockIdx.x * 512;
    int rend = min(r0 + 512, n);
    const unsigned int* hp = (const unsigned int*)hin;
    float s0 = 0.f, q0 = 0.f, s1 = 0.f, q1 = 0.f;
    for (int r = r0 + quarter; r < rend; r += 4) {
        unsigned int v = hp[(size_t)r * 64 + c2];
        float a = blo2f(v), b = bhi2f(v);
        s0 += a; q0 += a * a;
        s1 += b; q1 += b * b;
    }
    *(float4*)&red[quarter][c2 * 4] = make_float4(s0, q0, s1, q1);
    __syncthreads();
    float v = red[0][t] + red[1][t] + red[2][t] + red[3][t];
    int c2i = t >> 2, k = t & 3;
    int ch = c2i * 2 + (k >> 1);
    if (k & 1) atomicAdd(&sqs[ch], v);
    else       atomicAdd(&sums[ch], v);
}

// ---------------- output head: BN+ELU on bf16 in, in-block BN finalize ----------------
__global__ __launch_bounds__(256) void k_outgemm(const unsigned short* __restrict__ h,
                                                 const float* __restrict__ sums,
                                                 const float* __restrict__ sqs,
                                                 const float* __restrict__ gamma,
                                                 const float* __restrict__ beta,
                                                 const float* __restrict__ Wout,
                                                 const float* __restrict__ bout,
                                                 float* __restrict__ out, int n) {
    __shared__ float lwT[40][128];
    __shared__ float lh[64][132];
    __shared__ float lb[40];
    __shared__ float lsc[128], lsh[128];
    int t = threadIdx.x;
    if (t < 128) {
        float mu = sums[t] * (1.f / NNODES);
        float var = fmaxf(sqs[t] * (1.f / NNODES) - mu * mu, 0.f);
        float s = gamma[t] * rsqrtf(var + BNEPS);
        lsc[t] = s;
        lsh[t] = beta[t] - mu * s;
    }
    for (int idx = t; idx < 128 * 40; idx += 256) {
        int r = idx / 40, c = idx % 40;
        lwT[c][r] = Wout[idx];
    }
    if (t < 40) lb[t] = bout[t];
    __syncthreads();
    int n0 = blockIdx.x * 64;
    const uint4* hb4 = (const uint4*)h;
#pragma unroll
    for (int j = 0; j < 4; j++) {
        int idx = t + j * 256;
        int r = idx >> 4, seg = idx & 15;
        uint4 v = make_uint4(0, 0, 0, 0);
        if (n0 + r < n) v = hb4[(size_t)(n0 + r) * 16 + seg];
        float f[8];
        f[0] = blo2f(v.x); f[1] = bhi2f(v.x);
        f[2] = blo2f(v.y); f[3] = bhi2f(v.y);
        f[4] = blo2f(v.z); f[5] = bhi2f(v.z);
        f[6] = blo2f(v.w); f[7] = bhi2f(v.w);
#pragma unroll
        for (int k = 0; k < 8; k++) {
            int c = seg * 8 + k;
            float z = fmaf(f[k], lsc[c], lsh[c]);
            z = z > 0.f ? z : __expf(z) - 1.f;
            lh[r][c] = z;
        }
    }
    __syncthreads();
    int nl = t & 63, g = t >> 6;
    int row = n0 + nl;
    if (row >= n) return;
    float acc[10] = {};
    for (int k = 0; k < 128; k += 4) {
        float4 hv = *(const float4*)&lh[nl][k];
#pragma unroll
        for (int j = 0; j < 10; j++) {
            float4 wv = *(const float4*)&lwT[g * 10 + j][k];
            acc[j] += hv.x * wv.x + hv.y * wv.y + hv.z * wv.z + hv.w * wv.w;
        }
    }
#pragma unroll
    for (int j = 0; j < 10; j++)
        out[(size_t)row * 40 + g * 10 + j] = acc[j] + lb[g * 10 + j];
}

// ---------------- launch ----------------
extern "C" void kernel_launch(void* const* d_in, const int* in_sizes, int n_in,
                              void* d_out, int out_size, void* d_ws, size_t ws_size,
                              hipStream_t stream) {
    const float* x      = (const float*)d_in[0];
    const int*   ei     = (const int*)d_in[1];
    const float* W1     = (const float*)d_in[2];
    const float* a_src1 = (const float*)d_in[3];
    const float* a_dst1 = (const float*)d_in[4];
    const float* b1     = (const float*)d_in[5];
    const float* W2     = (const float*)d_in[6];
    const float* a_src2 = (const float*)d_in[7];
    const float* a_dst2 = (const float*)d_in[8];
    const float* b2     = (const float*)d_in[9];
    const float* gamma  = (const float*)d_in[10];
    const float* beta   = (const float*)d_in[11];
    const float* Wout   = (const float*)d_in[12];
    const float* bout   = (const float*)d_in[13];
    float* out = (float*)d_out;

    char* p = (char*)d_ws;
    auto alloc = [&](size_t bytes) -> void* {
        void* r = (void*)p;
        p += (bytes + 255) & ~(size_t)255;
        return r;
    };
    unsigned short* hB    = (unsigned short*)alloc((size_t)NNODES * 128 * 2);
    unsigned short* haggB = (unsigned short*)alloc((size_t)NNODES * 128 * 2);
    float* es     = (float*)alloc((size_t)NNODES * 4);
    float* ed     = (float*)alloc((size_t)NNODES * 4);
    int*   pairs  = (int*)alloc((size_t)ET * 4);
    int*   srcs   = (int*)alloc((size_t)ET * 4);
    int*   rowptr = (int*)alloc((size_t)(NNODES + 1) * 4);
    int*   bcnt   = (int*)alloc(256 * 4);
    int*   bbase  = (int*)alloc(256 * 4);
    int*   bcur   = (int*)alloc(256 * 4);
    float* bnstat = (float*)alloc(4 * 128 * 4);
    unsigned short* WT1 = (unsigned short*)alloc(128 * 128 * 2);
    unsigned short* WT2 = (unsigned short*)alloc(128 * 128 * 2);
    int*   flag   = (int*)alloc(4);

    float* sum1 = bnstat, *sq1 = bnstat + 128, *sum2 = bnstat + 256, *sq2 = bnstat + 384;

    hipMemsetAsync(bcnt, 0, 256 * 4, stream);
    hipMemsetAsync(bnstat, 0, 4 * 128 * 4, stream);

    k_prep<<<64, 256, 0, stream>>>(W1, W2, WT1, WT2, ei, flag);
    k_bhist<<<NBLK_E, 256, 0, stream>>>(ei, flag, bcnt);
    k_bscan<<<1, 256, 0, stream>>>(bcnt, bbase, bcur);
    k_bscatter<<<NBLK_E, 256, 0, stream>>>(ei, flag, bcur, pairs);
    k_bsort<<<NBUCK, 256, 0, stream>>>(pairs, bbase, rowptr, srcs);

    const int GB = (NNODES + 63) / 64;            // 1563
    const int AB = NNODES / 8;                    // 12500 (8 nodes/block)
    const int SB = (NNODES + 511) / 512;          // 196

    // ---- layer 1 ----
    k_gemm<false><<<GB, 256, 0, stream>>>(x, WT1, nullptr, nullptr, nullptr, nullptr,
                                          a_src1, a_dst1, es, ed, hB, NNODES);
    k_attn<<<AB, 256, 0, stream>>>(hB, srcs, rowptr, es, ed, b1, haggB, NNODES);
    k_bnstats<<<SB, 256, 0, stream>>>(haggB, sum1, sq1, NNODES);

    // ---- layer 2 (BN+ELU finalized+fused in A-staging) ----
    k_gemm<true><<<GB, 256, 0, stream>>>(haggB, WT2, sum1, sq1, gamma, beta,
                                         a_src2, a_dst2, es, ed, hB, NNODES);
    k_attn<<<AB, 256, 0, stream>>>(hB, srcs, rowptr, es, ed, b2, haggB, NNODES);
    k_bnstats<<<SB, 256, 0, stream>>>(haggB, sum2, sq2, NNODES);

    // ---- head (BN finalize + ELU fused into staging) ----
    k_outgemm<<<GB, 256, 0, stream>>>(haggB, sum2, sq2, gamma, beta, Wout, bout, out, NNODES);

    (void)in_sizes; (void)n_in; (void)out_size; (void)ws_size;
}

// Round 5
// 485.266 us; speedup vs baseline: 2.1622x; 1.0132x over previous
//
#include <hip/hip_runtime.h>

#define NNODES 100000
#define NEDGES 1600000
#define ET (NEDGES + NNODES)      // 1,700,000 incl. self loops
#define NBUCK 196                 // ceil(100000/512) buckets of 512 nodes
#define NEG 0.2f
#define BNEPS 1e-5f
#define EPB 16384                 // edges per block, bucket passes
#define NBLK_E ((ET + EPB - 1) / EPB)   // 104

typedef __attribute__((ext_vector_type(8))) short short8;
typedef __attribute__((ext_vector_type(4))) float floatx4;
typedef __attribute__((ext_vector_type(2))) float floatx2;

__device__ __forceinline__ unsigned short f2b(float x) {
    unsigned int u = __float_as_uint(x);
    u += 0x7fff + ((u >> 16) & 1);        // RNE
    return (unsigned short)(u >> 16);
}
__device__ __forceinline__ float b2f(unsigned short u) {
    return __uint_as_float(((unsigned int)u) << 16);
}
__device__ __forceinline__ float blo2f(unsigned int v) {
    return __uint_as_float(v << 16);
}
__device__ __forceinline__ float bhi2f(unsigned int v) {
    return __uint_as_float(v & 0xffff0000u);
}
__device__ __forceinline__ floatx2 u2f2(unsigned int v) {
    floatx2 r;
    r.x = __uint_as_float(v << 16);
    r.y = __uint_as_float(v & 0xffff0000u);
    return r;
}

// ---------------- edge decode (int32 vs int64 hedge) ----------------
__device__ __forceinline__ int edge_src(const int* ei, int e, int w64) {
    if (e >= NEDGES) return e - NEDGES;          // self loop
    return w64 ? ei[2 * e] : ei[e];
}
__device__ __forceinline__ int edge_dst(const int* ei, int e, int w64) {
    if (e >= NEDGES) return e - NEDGES;
    return w64 ? ei[2 * (NEDGES + e)] : ei[NEDGES + e];
}

// ---------------- prep: dtype detect + W transpose + scratch zeroing ----------------
__global__ void k_prep(const float* __restrict__ W1, const float* __restrict__ W2,
                       unsigned short* __restrict__ WT1, unsigned short* __restrict__ WT2,
                       const int* ei, int* flag, int* bcnt, int* done, float* bnstat) {
    int t = blockIdx.x * 256 + threadIdx.x;      // 16384 threads
    if (blockIdx.x == 0) {
        bcnt[threadIdx.x] = 0;
        if (threadIdx.x == 0) *done = 0;
        if (threadIdx.x == 1) {
            int is64 = 1;
            for (int j = 1; j < 16; j += 2)
                if (ei[j] != 0) is64 = 0;
            *flag = is64;
        }
    } else if (blockIdx.x == 1) {
        bnstat[threadIdx.x] = 0.f;
    } else if (blockIdx.x == 2) {
        bnstat[256 + threadIdx.x] = 0.f;
    }
    int k = t >> 7, n = t & 127;
    WT1[n * 128 + k] = f2b(W1[t]);
    WT2[n * 128 + k] = f2b(W2[t]);
}

// ---------------- CSR build pass A: bucket histogram (+inline scan, last block) ----
__global__ __launch_bounds__(256) void k_bhist(const int* __restrict__ ei,
                                               const int* flag, int* bcnt,
                                               int* done, int* bbase, int* bcur) {
    __shared__ int lc[256];
    __shared__ int lastf;
    int t = threadIdx.x;
    lc[t] = 0;
    __syncthreads();
    int w64 = *flag;
    int base = blockIdx.x * EPB;
    for (int j = 0; j < EPB / 512; j++) {
        int e = base + j * 512 + t * 2;          // 2 edges per thread
        if (e + 1 < NEDGES) {
            int d0, d1;
            if (w64) {
                int4 dv = *(const int4*)&ei[2 * (NEDGES + e)];
                d0 = dv.x; d1 = dv.z;
            } else {
                int2 dv = *(const int2*)&ei[NEDGES + e];
                d0 = dv.x; d1 = dv.y;
            }
            atomicAdd(&lc[d0 >> 9], 1);
            atomicAdd(&lc[d1 >> 9], 1);
        } else {
            for (int k = 0; k < 2; k++) {
                int ee = e + k;
                if (ee < ET) atomicAdd(&lc[edge_dst(ei, ee, w64) >> 9], 1);
            }
        }
    }
    __syncthreads();
    if (t < NBUCK && lc[t]) atomicAdd(&bcnt[t], lc[t]);
    __threadfence();
    __syncthreads();
    if (t == 0) lastf = (atomicAdd(done, 1) == gridDim.x - 1) ? 1 : 0;
    __syncthreads();
    if (!lastf) return;
    // inline 196-bucket exclusive scan
    int v = (t < NBUCK) ? atomicAdd(&bcnt[t], 0) : 0;
    __syncthreads();
    lc[t] = v;
    __syncthreads();
    for (int off = 1; off < 256; off <<= 1) {
        int add = (t >= off) ? lc[t - off] : 0;
        __syncthreads();
        lc[t] += add;
        __syncthreads();
    }
    int excl = lc[t] - v;
    if (t < NBUCK) { bbase[t] = excl; bcur[t] = excl; }
    if (t == NBUCK - 1) bbase[NBUCK] = excl + v;
}

// ---------------- pass C: partition packed pairs into bucket regions ----------------
// pairs packed: (src << 9) | (dst & 511); src < 2^17
__global__ __launch_bounds__(256) void k_bscatter(const int* __restrict__ ei,
                                                  const int* flag, int* bcur,
                                                  int* __restrict__ pairs) {
    __shared__ int lc[256];
    __shared__ int lbase[256];
    int t = threadIdx.x;
    lc[t] = 0;
    __syncthreads();
    int w64 = *flag;
    int base = blockIdx.x * EPB;
    for (int j = 0; j < EPB / 512; j++) {
        int e = base + j * 512 + t * 2;
        if (e + 1 < NEDGES) {
            int d0, d1;
            if (w64) {
                int4 dv = *(const int4*)&ei[2 * (NEDGES + e)];
                d0 = dv.x; d1 = dv.z;
            } else {
                int2 dv = *(const int2*)&ei[NEDGES + e];
                d0 = dv.x; d1 = dv.y;
            }
            atomicAdd(&lc[d0 >> 9], 1);
            atomicAdd(&lc[d1 >> 9], 1);
        } else {
            for (int k = 0; k < 2; k++) {
                int ee = e + k;
                if (ee < ET) atomicAdd(&lc[edge_dst(ei, ee, w64) >> 9], 1);
            }
        }
    }
    __syncthreads();
    if (t < NBUCK && lc[t]) lbase[t] = atomicAdd(&bcur[t], lc[t]);
    __syncthreads();
    for (int j = 0; j < EPB / 512; j++) {
        int e = base + j * 512 + t * 2;
        if (e + 1 < NEDGES) {
            int s0, s1, d0, d1;
            if (w64) {
                int4 sv = *(const int4*)&ei[2 * e];
                int4 dv = *(const int4*)&ei[2 * (NEDGES + e)];
                s0 = sv.x; s1 = sv.z; d0 = dv.x; d1 = dv.z;
            } else {
                int2 sv = *(const int2*)&ei[e];
                int2 dv = *(const int2*)&ei[NEDGES + e];
                s0 = sv.x; s1 = sv.y; d0 = dv.x; d1 = dv.y;
            }
            int p0 = atomicAdd(&lbase[d0 >> 9], 1);
            pairs[p0] = (s0 << 9) | (d0 & 511);
            int p1 = atomicAdd(&lbase[d1 >> 9], 1);
            pairs[p1] = (s1 << 9) | (d1 & 511);
        } else {
            for (int k = 0; k < 2; k++) {
                int ee = e + k;
                if (ee < ET) {
                    int src = edge_src(ei, ee, w64);
                    int dst = edge_dst(ei, ee, w64);
                    int pos = atomicAdd(&lbase[dst >> 9], 1);
                    pairs[pos] = (src << 9) | (dst & 511);
                }
            }
        }
    }
}

// ---------------- pass D: per-bucket counting sort -> rowptr + srcs ----------------
__global__ __launch_bounds__(256) void k_bsort(const int* __restrict__ pairs,
                                               const int* __restrict__ bbase,
                                               int* __restrict__ rowptr,
                                               int* __restrict__ srcs) {
    __shared__ int ncnt[512];
    __shared__ int nbase[512];
    __shared__ int stmp[256];
    int b = blockIdx.x, t = threadIdx.x;
    ncnt[t] = 0; ncnt[t + 256] = 0;
    __syncthreads();
    int s0 = bbase[b], s1 = bbase[b + 1];
    for (int i = s0 + t; i < s1; i += 256)
        atomicAdd(&ncnt[pairs[i] & 511], 1);
    __syncthreads();
    int c0 = ncnt[2 * t], c1 = ncnt[2 * t + 1];
    int s = c0 + c1;
    stmp[t] = s;
    __syncthreads();
    for (int off = 1; off < 256; off <<= 1) {
        int add = (t >= off) ? stmp[t - off] : 0;
        __syncthreads();
        stmp[t] += add;
        __syncthreads();
    }
    int excl = stmp[t] - s;
    nbase[2 * t] = excl;
    nbase[2 * t + 1] = excl + c0;
    __syncthreads();
    for (int l = t; l < 512; l += 256) {
        int node = b * 512 + l;
        if (node <= NNODES) rowptr[node] = s0 + nbase[l];
        ncnt[l] = nbase[l];            // becomes cursor
    }
    __syncthreads();
    for (int i = s0 + t; i < s1; i += 256) {
        int pr = pairs[i];
        int off = atomicAdd(&ncnt[pr & 511], 1);
        srcs[s0 + off] = ((unsigned int)pr) >> 9;
    }
}

// ---------------- MFMA GEMM (+in-block BN/ELU on bf16 A) + fused scores ----------------
template<bool BN>
__global__ __launch_bounds__(256) void k_gemm(const void* __restrict__ Ain,
        const unsigned short* __restrict__ WTg,
        const float* __restrict__ sums, const float* __restrict__ sqs,
        const float* __restrict__ gamma, const float* __restrict__ beta,
        const float* __restrict__ a_s, const float* __restrict__ a_d,
        float* __restrict__ es, float* __restrict__ ed,
        unsigned short* __restrict__ hB, int n) {
    __shared__ unsigned short lA[64][136];
    __shared__ unsigned short lW[128][136];
    __shared__ float las[128], lad[128];
    __shared__ float lsc[128], lsh[128];
    int t = threadIdx.x;
    int row0 = blockIdx.x * 64;
    if (t < 128) { las[t] = a_s[t]; lad[t] = a_d[t]; }
    if (BN && t < 128) {
        float mu = sums[t] * (1.f / NNODES);
        float var = fmaxf(sqs[t] * (1.f / NNODES) - mu * mu, 0.f);
        float s = gamma[t] * rsqrtf(var + BNEPS);
        lsc[t] = s;
        lsh[t] = beta[t] - mu * s;
    }

    const uint4* wt4 = (const uint4*)WTg;
#pragma unroll
    for (int j = 0; j < 8; j++) {
        int idx = t + j * 256;
        *(uint4*)&lW[idx >> 4][(idx & 15) * 8] = wt4[idx];
    }
    if (BN) __syncthreads();   // lsc/lsh visible before A staging

    if (BN) {
        const uint4* Ab = (const uint4*)Ain;   // bf16 rows, 16 uint4 each
#pragma unroll
        for (int j = 0; j < 4; j++) {
            int idx = t + j * 256;
            int r = idx >> 4, seg = idx & 15;
            uint4 v = make_uint4(0, 0, 0, 0);
            if (row0 + r < n) v = Ab[(size_t)(row0 + r) * 16 + seg];
            float f[8];
            f[0] = blo2f(v.x); f[1] = bhi2f(v.x);
            f[2] = blo2f(v.y); f[3] = bhi2f(v.y);
            f[4] = blo2f(v.z); f[5] = bhi2f(v.z);
            f[6] = blo2f(v.w); f[7] = bhi2f(v.w);
            ushort4 u0, u1;
            unsigned short us[8];
#pragma unroll
            for (int k = 0; k < 8; k++) {
                int c = seg * 8 + k;
                float z = fmaf(f[k], lsc[c], lsh[c]);
                z = z > 0.f ? z : __expf(z) - 1.f;
                us[k] = f2b(z);
            }
            u0.x = us[0]; u0.y = us[1]; u0.z = us[2]; u0.w = us[3];
            u1.x = us[4]; u1.y = us[5]; u1.z = us[6]; u1.w = us[7];
            *(ushort4*)&lA[r][seg * 8] = u0;
            *(ushort4*)&lA[r][seg * 8 + 4] = u1;
        }
    } else {
        const float* Af = (const float*)Ain;
#pragma unroll
        for (int j = 0; j < 8; j++) {
            int idx = t + j * 256;
            int r = idx >> 5, c4 = idx & 31;
            float4 v = make_float4(0.f, 0.f, 0.f, 0.f);
            if (row0 + r < n) v = ((const float4*)Af)[(size_t)(row0 + r) * 32 + c4];
            ushort4 u;
            u.x = f2b(v.x); u.y = f2b(v.y); u.z = f2b(v.z); u.w = f2b(v.w);
            *(ushort4*)&lA[r][c4 * 4] = u;
        }
    }
    __syncthreads();

    int w = t >> 6, lane = t & 63;
    int m = lane & 15, q = lane >> 4;
    int arow = w * 16 + m;
    floatx4 acc[8];
#pragma unroll
    for (int ct = 0; ct < 8; ct++) acc[ct] = (floatx4)0.0f;

#pragma unroll
    for (int kt = 0; kt < 4; kt++) {
        int kb = kt * 32 + q * 8;
        short8 af = *(const short8*)&lA[arow][kb];
#pragma unroll
        for (int ct = 0; ct < 8; ct++) {
            short8 bf = *(const short8*)&lW[ct * 16 + m][kb];
            acc[ct] = __builtin_amdgcn_mfma_f32_16x16x32_bf16(af, bf, acc[ct], 0, 0, 0);
        }
    }

    __syncthreads();   // done reading lA as input; about to overwrite with C tile
#pragma unroll
    for (int ct = 0; ct < 8; ct++)
#pragma unroll
        for (int r = 0; r < 4; r++)
            lA[w * 16 + q * 4 + r][ct * 16 + m] = f2b(acc[ct][r]);
#pragma unroll
    for (int j = 0; j < 4; j++) {
        int idx = lane + j * 64;
        int r = idx >> 4, seg = idx & 15;
        int grow = row0 + w * 16 + r;
        if (grow < n) {
            uint4 v = *(const uint4*)&lA[w * 16 + r][seg * 8];
            ((uint4*)hB)[(size_t)grow * 16 + seg] = v;
        }
    }
    __syncthreads();
    // fused attention scores: 4 threads per row, 32 chans each
    int r = t >> 2, q4 = t & 3;
    float s1 = 0.f, s2 = 0.f;
#pragma unroll
    for (int k = 0; k < 32; k++) {
        int c = q4 * 32 + k;
        float v = b2f(lA[r][c]);
        s1 += v * las[c];
        s2 += v * lad[c];
    }
    s1 += __shfl_xor(s1, 1, 64); s1 += __shfl_xor(s1, 2, 64);
    s2 += __shfl_xor(s2, 1, 64); s2 += __shfl_xor(s2, 2, 64);
    if (q4 == 0 && row0 + r < n) { es[row0 + r] = s1; ed[row0 + r] = s2; }
}

// ---------------- fused softmax + weighted gather (quarter-wave per node) ----------
// 16 lanes = exactly one 256B row; no acc cross-reduction, no gather guards.
// one-pass softmax: scores bounded (|e| << 88) so exp() direct is exact math.
__global__ __launch_bounds__(256) void k_attn(const unsigned short* __restrict__ hB,
                                              const int* __restrict__ srcs,
                                              const int* __restrict__ rowptr,
                                              const float* __restrict__ es,
                                              const float* __restrict__ ed,
                                              const float* __restrict__ bias,
                                              unsigned short* __restrict__ haggB, int n) {
    int w = (blockIdx.x * 256 + threadIdx.x) >> 4;   // node per quarter-wave
    if (w >= n) return;
    int l = threadIdx.x & 15;
    int qb = threadIdx.x & 48;                       // quarter's base lane in wave
    int start = rowptr[w], end = rowptr[w + 1];
    float edv = ed[w];
    const uint4* hp4 = (const uint4*)hB;
    floatx2 a0 = {0.f, 0.f}, a1 = {0.f, 0.f}, a2 = {0.f, 0.f}, a3 = {0.f, 0.f};
    float den = 0.f;

    for (int chunk = start; chunk < end; chunk += 16) {
        int i = chunk + l;
        int sv = 0; float pv = 0.f;
        if (i < end) {
            sv = srcs[i];
            float e = es[sv] + edv;
            e = e > 0.f ? e : NEG * e;
            pv = __expf(e);
            den += pv;
        }
        int cnt = min(16, end - chunk);
        for (int j = 0; j < cnt; j++) {
            int   s0 = __shfl(sv, qb + j, 64);
            float p0 = __shfl(pv, qb + j, 64);
            uint4 h0 = hp4[(size_t)s0 * 16 + l];
            floatx2 P = {p0, p0};
            a0 += P * u2f2(h0.x); a1 += P * u2f2(h0.y);
            a2 += P * u2f2(h0.z); a3 += P * u2f2(h0.w);
        }
    }
    den += __shfl_xor(den, 1, 64); den += __shfl_xor(den, 2, 64);
    den += __shfl_xor(den, 4, 64); den += __shfl_xor(den, 8, 64);
    float inv = 1.f / den;                           // den > 0: self loop guaranteed
    const float2* b2p = (const float2*)bias;
    float2 c0 = b2p[l * 4 + 0], c1 = b2p[l * 4 + 1];
    float2 c2 = b2p[l * 4 + 2], c3 = b2p[l * 4 + 3];
    uint4 o;
    o.x = (unsigned int)f2b(fmaf(a0.x, inv, c0.x)) |
          ((unsigned int)f2b(fmaf(a0.y, inv, c0.y)) << 16);
    o.y = (unsigned int)f2b(fmaf(a1.x, inv, c1.x)) |
          ((unsigned int)f2b(fmaf(a1.y, inv, c1.y)) << 16);
    o.z = (unsigned int)f2b(fmaf(a2.x, inv, c2.x)) |
          ((unsigned int)f2b(fmaf(a2.y, inv, c2.y)) << 16);
    o.w = (unsigned int)f2b(fmaf(a3.x, inv, c3.x)) |
          ((unsigned int)f2b(fmaf(a3.y, inv, c3.y)) << 16);
    ((uint4*)haggB)[(size_t)w * 16 + l] = o;
}

// ---------------- BatchNorm stats from bf16 hagg ----------------
__global__ __launch_bounds__(256) void k_bnstats(const unsigned short* __restrict__ hin,
                                                 float* sums, float* sqs, int n) {
    __shared__ float red[4][256];
    int t = threadIdx.x;
    int c2 = t & 63, quarter = t >> 6;
    int r0 = blockIdx.x * 512;
    int rend = min(r0 + 512, n);
    const unsigned int* hp = (const unsigned int*)hin;
    float s0 = 0.f, q0 = 0.f, s1 = 0.f, q1 = 0.f;
    for (int r = r0 + quarter; r < rend; r += 4) {
        unsigned int v = hp[(size_t)r * 64 + c2];
        float a = blo2f(v), b = bhi2f(v);
        s0 += a; q0 += a * a;
        s1 += b; q1 += b * b;
    }
    *(float4*)&red[quarter][c2 * 4] = make_float4(s0, q0, s1, q1);
    __syncthreads();
    float v = red[0][t] + red[1][t] + red[2][t] + red[3][t];
    int c2i = t >> 2, k = t & 3;
    int ch = c2i * 2 + (k >> 1);
    if (k & 1) atomicAdd(&sqs[ch], v);
    else       atomicAdd(&sums[ch], v);
}

// ---------------- output head: BN+ELU on bf16 in, in-block BN finalize ----------------
__global__ __launch_bounds__(256) void k_outgemm(const unsigned short* __restrict__ h,
                                                 const float* __restrict__ sums,
                                                 const float* __restrict__ sqs,
                                                 const float* __restrict__ gamma,
                                                 const float* __restrict__ beta,
                                                 const float* __restrict__ Wout,
                                                 const float* __restrict__ bout,
                                                 float* __restrict__ out, int n) {
    __shared__ float lwT[40][128];
    __shared__ float lh[64][132];
    __shared__ float lb[40];
    __shared__ float lsc[128], lsh[128];
    int t = threadIdx.x;
    if (t < 128) {
        float mu = sums[t] * (1.f / NNODES);
        float var = fmaxf(sqs[t] * (1.f / NNODES) - mu * mu, 0.f);
        float s = gamma[t] * rsqrtf(var + BNEPS);
        lsc[t] = s;
        lsh[t] = beta[t] - mu * s;
    }
    for (int idx = t; idx < 128 * 40; idx += 256) {
        int r = idx / 40, c = idx % 40;
        lwT[c][r] = Wout[idx];
    }
    if (t < 40) lb[t] = bout[t];
    __syncthreads();
    int n0 = blockIdx.x * 64;
    const uint4* hb4 = (const uint4*)h;
#pragma unroll
    for (int j = 0; j < 4; j++) {
        int idx = t + j * 256;
        int r = idx >> 4, seg = idx & 15;
        uint4 v = make_uint4(0, 0, 0, 0);
        if (n0 + r < n) v = hb4[(size_t)(n0 + r) * 16 + seg];
        float f[8];
        f[0] = blo2f(v.x); f[1] = bhi2f(v.x);
        f[2] = blo2f(v.y); f[3] = bhi2f(v.y);
        f[4] = blo2f(v.z); f[5] = bhi2f(v.z);
        f[6] = blo2f(v.w); f[7] = bhi2f(v.w);
#pragma unroll
        for (int k = 0; k < 8; k++) {
            int c = seg * 8 + k;
            float z = fmaf(f[k], lsc[c], lsh[c]);
            z = z > 0.f ? z : __expf(z) - 1.f;
            lh[r][c] = z;
        }
    }
    __syncthreads();
    int nl = t & 63, g = t >> 6;
    int row = n0 + nl;
    if (row >= n) return;
    float acc[10] = {};
    for (int k = 0; k < 128; k += 4) {
        float4 hv = *(const float4*)&lh[nl][k];
#pragma unroll
        for (int j = 0; j < 10; j++) {
            float4 wv = *(const float4*)&lwT[g * 10 + j][k];
            acc[j] += hv.x * wv.x + hv.y * wv.y + hv.z * wv.z + hv.w * wv.w;
        }
    }
#pragma unroll
    for (int j = 0; j < 10; j++)
        out[(size_t)row * 40 + g * 10 + j] = acc[j] + lb[g * 10 + j];
}

// ---------------- launch ----------------
extern "C" void kernel_launch(void* const* d_in, const int* in_sizes, int n_in,
                              void* d_out, int out_size, void* d_ws, size_t ws_size,
                              hipStream_t stream) {
    const float* x      = (const float*)d_in[0];
    const int*   ei     = (const int*)d_in[1];
    const float* W1     = (const float*)d_in[2];
    const float* a_src1 = (const float*)d_in[3];
    const float* a_dst1 = (const float*)d_in[4];
    const float* b1     = (const float*)d_in[5];
    const float* W2     = (const float*)d_in[6];
    const float* a_src2 = (const float*)d_in[7];
    const float* a_dst2 = (const float*)d_in[8];
    const float* b2     = (const float*)d_in[9];
    const float* gamma  = (const float*)d_in[10];
    const float* beta   = (const float*)d_in[11];
    const float* Wout   = (const float*)d_in[12];
    const float* bout   = (const float*)d_in[13];
    float* out = (float*)d_out;

    char* p = (char*)d_ws;
    auto alloc = [&](size_t bytes) -> void* {
        void* r = (void*)p;
        p += (bytes + 255) & ~(size_t)255;
        return r;
    };
    unsigned short* hB    = (unsigned short*)alloc((size_t)NNODES * 128 * 2);
    unsigned short* haggB = (unsigned short*)alloc((size_t)NNODES * 128 * 2);
    float* es     = (float*)alloc((size_t)NNODES * 4);
    float* ed     = (float*)alloc((size_t)NNODES * 4);
    int*   pairs  = (int*)alloc((size_t)ET * 4);
    int*   srcs   = (int*)alloc((size_t)ET * 4);
    int*   rowptr = (int*)alloc((size_t)(NNODES + 1) * 4);
    int*   bcnt   = (int*)alloc(256 * 4);
    int*   bbase  = (int*)alloc(256 * 4);
    int*   bcur   = (int*)alloc(256 * 4);
    float* bnstat = (float*)alloc(4 * 128 * 4);
    unsigned short* WT1 = (unsigned short*)alloc(128 * 128 * 2);
    unsigned short* WT2 = (unsigned short*)alloc(128 * 128 * 2);
    int*   flag   = (int*)alloc(4);
    int*   done   = (int*)alloc(4);

    float* sum1 = bnstat, *sq1 = bnstat + 128, *sum2 = bnstat + 256, *sq2 = bnstat + 384;

    k_prep<<<64, 256, 0, stream>>>(W1, W2, WT1, WT2, ei, flag, bcnt, done, bnstat);
    k_bhist<<<NBLK_E, 256, 0, stream>>>(ei, flag, bcnt, done, bbase, bcur);
    k_bscatter<<<NBLK_E, 256, 0, stream>>>(ei, flag, bcur, pairs);
    k_bsort<<<NBUCK, 256, 0, stream>>>(pairs, bbase, rowptr, srcs);

    const int GB = (NNODES + 63) / 64;            // 1563
    const int AB = NNODES / 16;                   // 6250 (16 nodes/block)
    const int SB = (NNODES + 511) / 512;          // 196

    // ---- layer 1 ----
    k_gemm<false><<<GB, 256, 0, stream>>>(x, WT1, nullptr, nullptr, nullptr, nullptr,
                                          a_src1, a_dst1, es, ed, hB, NNODES);
    k_attn<<<AB, 256, 0, stream>>>(hB, srcs, rowptr, es, ed, b1, haggB, NNODES);
    k_bnstats<<<SB, 256, 0, stream>>>(haggB, sum1, sq1, NNODES);

    // ---- layer 2 (BN+ELU finalized+fused in A-staging) ----
    k_gemm<true><<<GB, 256, 0, stream>>>(haggB, WT2, sum1, sq1, gamma, beta,
                                         a_src2, a_dst2, es, ed, hB, NNODES);
    k_attn<<<AB, 256, 0, stream>>>(hB, srcs, rowptr, es, ed, b2, haggB, NNODES);
    k_bnstats<<<SB, 256, 0, stream>>>(haggB, sum2, sq2, NNODES);

    // ---- head (BN finalize + ELU fused into staging) ----
    k_outgemm<<<GB, 256, 0, stream>>>(haggB, sum2, sq2, gamma, beta, Wout, bout, out, NNODES);

    (void)in_sizes; (void)n_in; (void)out_size; (void)ws_size;
}